// Round 6
// baseline (912.425 us; speedup 1.0000x reference)
//
#include <hip/hip_runtime.h>

// ---------------------------------------------------------------------------
// GCN forward on MI355X — round 6.
//  * CSR rows padded to multiples of 4 (16-B aligned), sentinel index N whose
//    xd weight is 0 and whose g1 row is 0 -> branchless int4-indexed gather.
//  * MLP phase k-outer: each wave reads Ws once (not once per row) -> 4x less
//    LDS vector traffic; Hs read as b128 broadcasts.
//  * Bucketed counting-sort CSR build (round 5), per-bucket slack for padding.
// ---------------------------------------------------------------------------

#define DD 64          // feature dim
#define DQ 16          // float4s per row
#define BKT 256        // nodes per bucket
#define MAXK 1024      // max buckets (N <= 262144)
#define SLACK 772      // per-bucket csr slack: 3*256 pad + 4 alignment

static __device__ __forceinline__ void atomAddF(float* p, float v) {
    unsafeAtomicAdd(p, v);   // global_atomic_add_f32 on gfx950
}

static __device__ __forceinline__ void f4fma(float4& a, float w, const float4& u) {
    a.x = fmaf(w, u.x, a.x); a.y = fmaf(w, u.y, a.y);
    a.z = fmaf(w, u.z, a.z); a.w = fmaf(w, u.w, a.w);
}
static __device__ __forceinline__ void f4add(float4& a, const float4& u) {
    a.x += u.x; a.y += u.y; a.z += u.z; a.w += u.w;
}

// ---- pass A: bucket histogram, segmented by blockIdx&7 (~XCD) -------------
__global__ __launch_bounds__(256) void bin_count_kernel(
        const int* __restrict__ dst, int E, int* __restrict__ hist, int K) {
    __shared__ int lh[MAXK];
    int tid = threadIdx.x;
    for (int i = tid; i < K; i += 256) lh[i] = 0;
    __syncthreads();
    int stride = gridDim.x * 256;
    for (int e = blockIdx.x * 256 + tid; e < E; e += stride)
        atomicAdd(&lh[((unsigned)dst[e]) >> 8], 1);
    __syncthreads();
    int seg = blockIdx.x & 7;
    for (int b = tid; b < K; b += 256) {
        int c = lh[b];
        if (c) atomicAdd(&hist[b * 8 + seg], c);
    }
}

// ---- pass B: exclusive scan of hist[M] -> cur (append cursors) + bnd ------
__global__ __launch_bounds__(256) void scan_kernel(
        const int* __restrict__ hist, int* __restrict__ cur,
        int* __restrict__ bnd, int M, int K, int E) {
    __shared__ int part[256];
    int tid = threadIdx.x;
    int CH = (M + 255) / 256;
    int base = tid * CH;
    int s = 0;
    for (int i = 0; i < CH; ++i) {
        int idx = base + i;
        if (idx < M) s += hist[idx];
    }
    part[tid] = s;
    __syncthreads();
    if (tid < 64) {
        int carry = 0;
        for (int c = 0; c < 4; ++c) {
            int orig = part[c * 64 + tid];
            int v = orig;
            #pragma unroll
            for (int off = 1; off < 64; off <<= 1) {
                int t = __shfl_up(v, off);
                if (tid >= off) v += t;
            }
            int tot = __shfl(v, 63);
            part[c * 64 + tid] = v - orig + carry;   // exclusive
            carry += tot;
        }
    }
    __syncthreads();
    int run = part[tid];
    for (int i = 0; i < CH; ++i) {
        int idx = base + i;
        if (idx < M) {
            cur[idx] = run;
            if ((idx & 7) == 0) bnd[idx >> 3] = run;
            run += hist[idx];
        }
    }
    if (tid == 0) bnd[K] = E;
}

// ---- pass C: append (src,dst) pairs into bucket segments ------------------
__global__ __launch_bounds__(256) void fill_pairs_kernel(
        const int* __restrict__ src, const int* __restrict__ dst, int E,
        int* __restrict__ cur, int2* __restrict__ pairbuf) {
    int e = blockIdx.x * 256 + threadIdx.x;
    if (e >= E) return;
    int s = src[e], d = dst[e];
    int seg = blockIdx.x & 7;
    int pos = atomicAdd(&cur[(((unsigned)d) >> 8) * 8 + seg], 1);
    pairbuf[pos] = make_int2(s, d);
}

// ---- pass D: per-bucket padded CSR build + cursor/pdeg/xd (coalesced) -----
// csr region for bucket b starts at align4(bnd[b]) + SLACK*b; rows padded to
// multiples of 4 with sentinel src index N.
__global__ __launch_bounds__(256) void build_csr_kernel(
        const int2* __restrict__ pairbuf, const int* __restrict__ bnd,
        const int* __restrict__ x, int* __restrict__ cursor,
        int* __restrict__ degcnt, float2* __restrict__ xd,
        int* __restrict__ csr_src, int N) {
    __shared__ int cnt[256], basel[256], curl[256];
    int tid = threadIdx.x;
    int b = blockIdx.x;
    int node0 = b << 8;
    cnt[tid] = 0;
    __syncthreads();
    int bb0 = bnd[b], bb1 = bnd[b + 1];
    for (int i = bb0 + tid; i < bb1; i += 256)
        atomicAdd(&cnt[pairbuf[i].y & 255], 1);
    __syncthreads();
    int c  = cnt[tid];
    int pc = (c + 3) & ~3;              // padded count
    // exclusive LDS scan of padded counts
    {
        __syncthreads();
        basel[tid] = pc;                // reuse as input
        __syncthreads();
        if (tid < 64) {
            int carry = 0;
            for (int cc = 0; cc < 4; ++cc) {
                int orig = basel[cc * 64 + tid];
                int v = orig;
                #pragma unroll
                for (int off = 1; off < 64; off <<= 1) {
                    int t = __shfl_up(v, off);
                    if (tid >= off) v += t;
                }
                int tot = __shfl(v, 63);
                cnt[cc * 64 + tid] = v - orig + carry;   // exclusive, into cnt[]
                carry += tot;
            }
        }
        __syncthreads();
    }
    int cb0 = ((bb0 + 3) & ~3) + SLACK * b;   // aligned csr base for bucket
    int node = node0 + tid;
    int myBase = cb0 + cnt[tid];
    curl[tid] = myBase;
    if (node < N) {
        cursor[node] = myBase;
        degcnt[node] = pc;
        xd[node] = make_float2(rsqrtf((float)c + 1.0f), __int_as_float(x[node]));
        for (int t = c; t < pc; ++t) csr_src[myBase + t] = N;   // sentinel pad
    } else if (node == N) {
        xd[N] = make_float2(0.0f, __int_as_float(0));           // zero weight
    }
    __syncthreads();
    for (int i = bb0 + tid; i < bb1; i += 256) {
        int2 p = pairbuf[i];
        int pos = atomicAdd(&curl[p.y & 255], 1);
        csr_src[pos] = p.x;
    }
}

// ---------------- layer 1: agg from embedding table, write g1 = dinv*h1 ----
__global__ __launch_bounds__(256) void layer1_kernel(
        const int* __restrict__ cursor, const int* __restrict__ deg,
        const int* __restrict__ csr_src, const float2* __restrict__ xd,
        const float4* __restrict__ table, const float* __restrict__ W,
        const float* __restrict__ bias, float* __restrict__ g1, int N) {
    __shared__ float Ws[DD * DD];   // 16 KB
    __shared__ float Hs[16 * DD];   // 4 KB
    __shared__ float dvs[16];
    int row0 = blockIdx.x * 16;
    int tid = threadIdx.x;
    {
        const float4* W4 = (const float4*)W;
        float4* Ws4 = (float4*)Ws;
        for (int k = tid; k < DD * DD / 4; k += 256) Ws4[k] = W4[k];
    }
    int node_l = tid >> 4, j = tid & 15;
    int node = row0 + node_l;
    float4 acc0 = make_float4(0.f, 0.f, 0.f, 0.f);
    float4 acc1 = acc0, acc2 = acc0, acc3 = acc0;
    if (node < N) {
        float2 sxd = xd[node];
        float di = sxd.x;
        if (j == 0) dvs[node_l] = di;
        float4 tv = table[(size_t)__float_as_int(sxd.y) * DQ + j];
        acc0.x = di * tv.x; acc0.y = di * tv.y;
        acc0.z = di * tv.z; acc0.w = di * tv.w;
        const int4* cs = (const int4*)(csr_src + cursor[node]);  // 16-B aligned
        int nq = deg[node] >> 2;                                 // padded groups
        for (int q = 0; q < nq; ++q) {
            int4 s4 = cs[q];
            float2 pa = xd[s4.x], pb = xd[s4.y], pc_ = xd[s4.z], pd = xd[s4.w];
            float4 u0 = table[(size_t)__float_as_int(pa.y) * DQ + j];
            float4 u1 = table[(size_t)__float_as_int(pb.y) * DQ + j];
            float4 u2 = table[(size_t)__float_as_int(pc_.y) * DQ + j];
            float4 u3 = table[(size_t)__float_as_int(pd.y) * DQ + j];
            f4fma(acc0, pa.x, u0); f4fma(acc1, pb.x, u1);
            f4fma(acc2, pc_.x, u2); f4fma(acc3, pd.x, u3);
        }
        f4add(acc0, acc1); f4add(acc2, acc3); f4add(acc0, acc2);
        acc0.x *= di; acc0.y *= di; acc0.z *= di; acc0.w *= di;
    }
    ((float4*)Hs)[node_l * DQ + j] = acc0;
    __syncthreads();

    // k-outer MLP: each wave reads Ws once; Hs via b128 broadcasts.
    int wave = tid >> 6, lane = tid & 63;
    int rbase = wave * 4;
    float b = bias[lane];
    float A0 = b, A1 = b, A2 = b, A3 = b;
    const float4* Hs4 = (const float4*)Hs;
    #pragma unroll
    for (int kb = 0; kb < 16; ++kb) {
        float4 h0 = Hs4[(rbase + 0) * 16 + kb];
        float4 h1 = Hs4[(rbase + 1) * 16 + kb];
        float4 h2 = Hs4[(rbase + 2) * 16 + kb];
        float4 h3 = Hs4[(rbase + 3) * 16 + kb];
        float w0 = Ws[(kb * 4 + 0) * DD + lane];
        float w1 = Ws[(kb * 4 + 1) * DD + lane];
        float w2 = Ws[(kb * 4 + 2) * DD + lane];
        float w3 = Ws[(kb * 4 + 3) * DD + lane];
        A0 = fmaf(h0.x, w0, A0); A0 = fmaf(h0.y, w1, A0);
        A0 = fmaf(h0.z, w2, A0); A0 = fmaf(h0.w, w3, A0);
        A1 = fmaf(h1.x, w0, A1); A1 = fmaf(h1.y, w1, A1);
        A1 = fmaf(h1.z, w2, A1); A1 = fmaf(h1.w, w3, A1);
        A2 = fmaf(h2.x, w0, A2); A2 = fmaf(h2.y, w1, A2);
        A2 = fmaf(h2.z, w2, A2); A2 = fmaf(h2.w, w3, A2);
        A3 = fmaf(h3.x, w0, A3); A3 = fmaf(h3.y, w1, A3);
        A3 = fmaf(h3.z, w2, A3); A3 = fmaf(h3.w, w3, A3);
    }
    if (row0 + rbase + 0 < N) g1[(size_t)(row0 + rbase + 0) * DD + lane] = dvs[rbase + 0] * fmaxf(A0, 0.0f);
    if (row0 + rbase + 1 < N) g1[(size_t)(row0 + rbase + 1) * DD + lane] = dvs[rbase + 1] * fmaxf(A1, 0.0f);
    if (row0 + rbase + 2 < N) g1[(size_t)(row0 + rbase + 2) * DD + lane] = dvs[rbase + 2] * fmaxf(A2, 0.0f);
    if (row0 + rbase + 3 < N) g1[(size_t)(row0 + rbase + 3) * DD + lane] = dvs[rbase + 3] * fmaxf(A3, 0.0f);
}

// -------- layer 2 + pool: agg2 = dinv_v*(g1[v] + sum g1[s]); h2@Wlin pooled --
__global__ __launch_bounds__(256) void layer2_pool_kernel(
        const int* __restrict__ cursor, const int* __restrict__ deg,
        const int* __restrict__ csr_src, const float2* __restrict__ xd,
        const float4* __restrict__ g1, const float* __restrict__ W,
        const float* __restrict__ bias, const int* __restrict__ batch,
        const float* __restrict__ Wlin, float* __restrict__ outacc, int N) {
    __shared__ float Ws[DD * DD];
    __shared__ float Hs[16 * DD];
    __shared__ float p0s[16], p1s[16];
    __shared__ int   bat[16];
    int row0 = blockIdx.x * 16;
    int tid = threadIdx.x;
    {
        const float4* W4 = (const float4*)W;
        float4* Ws4 = (float4*)Ws;
        for (int k = tid; k < DD * DD / 4; k += 256) Ws4[k] = W4[k];
    }
    int node_l = tid >> 4, j = tid & 15;
    int node = row0 + node_l;
    float4 acc0 = make_float4(0.f, 0.f, 0.f, 0.f);
    float4 acc1 = acc0, acc2 = acc0, acc3 = acc0;
    if (node < N) {
        float di = xd[node].x;
        acc0 = g1[(size_t)node * DQ + j];    // self term, weight 1
        const int4* cs = (const int4*)(csr_src + cursor[node]);
        int nq = deg[node] >> 2;
        for (int q = 0; q < nq; ++q) {
            int4 s4 = cs[q];
            float4 u0 = g1[(size_t)s4.x * DQ + j];
            float4 u1 = g1[(size_t)s4.y * DQ + j];
            float4 u2 = g1[(size_t)s4.z * DQ + j];
            float4 u3 = g1[(size_t)s4.w * DQ + j];
            f4add(acc0, u0); f4add(acc1, u1);
            f4add(acc2, u2); f4add(acc3, u3);
        }
        f4add(acc0, acc1); f4add(acc2, acc3); f4add(acc0, acc2);
        acc0.x *= di; acc0.y *= di; acc0.z *= di; acc0.w *= di;
    }
    ((float4*)Hs)[node_l * DQ + j] = acc0;
    __syncthreads();

    int wave = tid >> 6, lane = tid & 63;
    int rbase = wave * 4;
    float b = bias[lane];
    float A0 = b, A1 = b, A2 = b, A3 = b;
    const float4* Hs4 = (const float4*)Hs;
    #pragma unroll
    for (int kb = 0; kb < 16; ++kb) {
        float4 h0 = Hs4[(rbase + 0) * 16 + kb];
        float4 h1 = Hs4[(rbase + 1) * 16 + kb];
        float4 h2 = Hs4[(rbase + 2) * 16 + kb];
        float4 h3 = Hs4[(rbase + 3) * 16 + kb];
        float w0 = Ws[(kb * 4 + 0) * DD + lane];
        float w1 = Ws[(kb * 4 + 1) * DD + lane];
        float w2 = Ws[(kb * 4 + 2) * DD + lane];
        float w3 = Ws[(kb * 4 + 3) * DD + lane];
        A0 = fmaf(h0.x, w0, A0); A0 = fmaf(h0.y, w1, A0);
        A0 = fmaf(h0.z, w2, A0); A0 = fmaf(h0.w, w3, A0);
        A1 = fmaf(h1.x, w0, A1); A1 = fmaf(h1.y, w1, A1);
        A1 = fmaf(h1.z, w2, A1); A1 = fmaf(h1.w, w3, A1);
        A2 = fmaf(h2.x, w0, A2); A2 = fmaf(h2.y, w1, A2);
        A2 = fmaf(h2.z, w2, A2); A2 = fmaf(h2.w, w3, A2);
        A3 = fmaf(h3.x, w0, A3); A3 = fmaf(h3.y, w1, A3);
        A3 = fmaf(h3.z, w2, A3); A3 = fmaf(h3.w, w3, A3);
    }
    float wl0 = Wlin[lane * 2 + 0];
    float wl1 = Wlin[lane * 2 + 1];
    float Ar[4] = {A0, A1, A2, A3};
    #pragma unroll
    for (int rr = 0; rr < 4; ++rr) {
        int row = rbase + rr;
        int grow = row0 + row;
        float a = fmaxf(Ar[rr], 0.0f);
        float p0 = (grow < N) ? a * wl0 : 0.f;
        float p1 = (grow < N) ? a * wl1 : 0.f;
        #pragma unroll
        for (int off = 32; off >= 1; off >>= 1) {
            p0 += __shfl_xor(p0, off);
            p1 += __shfl_xor(p1, off);
        }
        if (lane == 0) {
            p0s[row] = p0;
            p1s[row] = p1;
            bat[row] = (grow < N) ? batch[grow] : -1;
        }
    }
    __syncthreads();
    if (tid < 16) {
        int bg = bat[tid];
        bool head = (bg >= 0) && (tid == 0 || bat[tid - 1] != bg);
        if (head) {
            float s0 = 0.f, s1 = 0.f;
            for (int k = tid; k < 16 && bat[k] == bg; ++k) {
                s0 += p0s[k];
                s1 += p1s[k];
            }
            atomAddF(&outacc[bg * 2 + 0], s0);
            atomAddF(&outacc[bg * 2 + 1], s1);
        }
    }
}

// counts via binary search on sorted batch; then divide + blin
__global__ void final_kernel(const float* __restrict__ outacc,
                             const int* __restrict__ batch,
                             const float* __restrict__ blin,
                             float* __restrict__ out, int G, int N) {
    int t = blockIdx.x * blockDim.x + threadIdx.x;
    if (t >= G * 2) return;
    int g = t >> 1, c = t & 1;
    int lo = 0, hi = N;
    while (lo < hi) { int m = (lo + hi) >> 1; if (batch[m] < g) lo = m + 1; else hi = m; }
    int lo2 = lo, hi2 = N;
    while (lo2 < hi2) { int m = (lo2 + hi2) >> 1; if (batch[m] < g + 1) lo2 = m + 1; else hi2 = m; }
    float cnt = (float)(lo2 - lo);
    out[t] = outacc[t] / fmaxf(cnt, 1.0f) + blin[c];
}

extern "C" void kernel_launch(void* const* d_in, const int* in_sizes, int n_in,
                              void* d_out, int out_size, void* d_ws, size_t ws_size,
                              hipStream_t stream) {
    const int*   x      = (const int*)d_in[0];
    const int*   ei     = (const int*)d_in[1];   // [2,E] row-major
    const int*   batch  = (const int*)d_in[3];
    const float* table  = (const float*)d_in[4];
    const float* W1     = (const float*)d_in[5];
    const float* b1     = (const float*)d_in[6];
    const float* W2     = (const float*)d_in[7];
    const float* b2     = (const float*)d_in[8];
    const float* Wlin   = (const float*)d_in[9];
    const float* blin   = (const float*)d_in[10];
    float* out = (float*)d_out;

    const int N = in_sizes[0];
    const int E = in_sizes[2];          // edge_type count == E
    const int G = out_size / 2;

    const int* src = ei;
    const int* dst = ei + E;

    const int K = (N + BKT - 1) / BKT;  // buckets
    const int M = K * 8;                // (bucket, seg) cells
    const int CSRSZ = E + SLACK * K + 64;

    // workspace layout
    size_t nh = (size_t)N * DD;
    float*  g1      = (float*)d_ws;                 // (N+1)*64 f32
    int2*   pairbuf = (int2*)(g1 + nh + DD);        // E int2
    int*    csr_src = (int*)(pairbuf + E);          // CSRSZ ints
    int*    cursor  = csr_src + CSRSZ;              // N
    int*    degcnt  = cursor + N;                   // N (padded deg)
    float2* xd      = (float2*)(degcnt + N);        // N+1 float2
    int*    hist    = (int*)(xd + N + 1);           // M
    int*    cur     = hist + M;                     // M
    int*    bnd     = cur + M;                      // K+1
    float*  outacc  = (float*)(bnd + K + 2);        // 2G

    const int BT = 256;

    hipMemsetAsync(hist, 0, (size_t)M * sizeof(int), stream);
    hipMemsetAsync(outacc, 0, (size_t)G * 2 * sizeof(float), stream);
    hipMemsetAsync(g1 + nh, 0, DD * sizeof(float), stream);   // zero row N

    // CSR build: histogram -> scan -> bucket append -> per-bucket sort (+pad)
    bin_count_kernel<<<256, BT, 0, stream>>>(dst, E, hist, K);
    scan_kernel<<<1, BT, 0, stream>>>(hist, cur, bnd, M, K, E);
    fill_pairs_kernel<<<(E + BT - 1) / BT, BT, 0, stream>>>(src, dst, E, cur, pairbuf);
    build_csr_kernel<<<K, BT, 0, stream>>>(pairbuf, bnd, x, cursor, degcnt, xd,
                                           csr_src, N);

    // layer 1 (embed+agg+GEMM+relu fused; writes g1 = dinv*h1)
    int gRow = (N + 15) / 16;
    layer1_kernel<<<gRow, BT, 0, stream>>>(cursor, degcnt, csr_src, xd,
                                           (const float4*)table, W1, b1, g1, N);
    // layer 2 (agg+GEMM+relu+pool fused)
    layer2_pool_kernel<<<gRow, BT, 0, stream>>>(cursor, degcnt, csr_src, xd,
                                                (const float4*)g1, W2, b2,
                                                batch, Wlin, outacc, N);
    // final
    final_kernel<<<(G * 2 + BT - 1) / BT, BT, 0, stream>>>(outacc, batch, blin,
                                                           out, G, N);
}

// Round 7
// 445.733 us; speedup vs baseline: 2.0470x; 2.0470x over previous
//
#include <hip/hip_runtime.h>

// ---------------------------------------------------------------------------
// GCN forward on MI355X — round 7.
//  * Round-6 padded branchless int4 gather KEPT (sentinel row N, aligned rows).
//  * MLP phase reverted to row-outer (round 5): 36 VGPR, high occupancy.
//    Round 6's k-outer unroll ballooned VGPRs 36->140, occupancy 65%->10%,
//    and the latency-bound gather lost all latency hiding (128->389 us).
//  * __launch_bounds__(256, 8) caps VGPR<=64 on both layer kernels.
// ---------------------------------------------------------------------------

#define DD 64          // feature dim
#define DQ 16          // float4s per row
#define BKT 256        // nodes per bucket
#define MAXK 1024      // max buckets (N <= 262144)
#define SLACK 772      // per-bucket csr slack: 3*256 pad + 4 alignment

static __device__ __forceinline__ void atomAddF(float* p, float v) {
    unsafeAtomicAdd(p, v);   // global_atomic_add_f32 on gfx950
}

static __device__ __forceinline__ void f4fma(float4& a, float w, const float4& u) {
    a.x = fmaf(w, u.x, a.x); a.y = fmaf(w, u.y, a.y);
    a.z = fmaf(w, u.z, a.z); a.w = fmaf(w, u.w, a.w);
}
static __device__ __forceinline__ void f4add(float4& a, const float4& u) {
    a.x += u.x; a.y += u.y; a.z += u.z; a.w += u.w;
}

// ---- pass A: bucket histogram, segmented by blockIdx&7 (~XCD) -------------
__global__ __launch_bounds__(256) void bin_count_kernel(
        const int* __restrict__ dst, int E, int* __restrict__ hist, int K) {
    __shared__ int lh[MAXK];
    int tid = threadIdx.x;
    for (int i = tid; i < K; i += 256) lh[i] = 0;
    __syncthreads();
    int stride = gridDim.x * 256;
    for (int e = blockIdx.x * 256 + tid; e < E; e += stride)
        atomicAdd(&lh[((unsigned)dst[e]) >> 8], 1);
    __syncthreads();
    int seg = blockIdx.x & 7;
    for (int b = tid; b < K; b += 256) {
        int c = lh[b];
        if (c) atomicAdd(&hist[b * 8 + seg], c);
    }
}

// ---- pass B: exclusive scan of hist[M] -> cur (append cursors) + bnd ------
__global__ __launch_bounds__(256) void scan_kernel(
        const int* __restrict__ hist, int* __restrict__ cur,
        int* __restrict__ bnd, int M, int K, int E) {
    __shared__ int part[256];
    int tid = threadIdx.x;
    int CH = (M + 255) / 256;
    int base = tid * CH;
    int s = 0;
    for (int i = 0; i < CH; ++i) {
        int idx = base + i;
        if (idx < M) s += hist[idx];
    }
    part[tid] = s;
    __syncthreads();
    if (tid < 64) {
        int carry = 0;
        for (int c = 0; c < 4; ++c) {
            int orig = part[c * 64 + tid];
            int v = orig;
            #pragma unroll
            for (int off = 1; off < 64; off <<= 1) {
                int t = __shfl_up(v, off);
                if (tid >= off) v += t;
            }
            int tot = __shfl(v, 63);
            part[c * 64 + tid] = v - orig + carry;   // exclusive
            carry += tot;
        }
    }
    __syncthreads();
    int run = part[tid];
    for (int i = 0; i < CH; ++i) {
        int idx = base + i;
        if (idx < M) {
            cur[idx] = run;
            if ((idx & 7) == 0) bnd[idx >> 3] = run;
            run += hist[idx];
        }
    }
    if (tid == 0) bnd[K] = E;
}

// ---- pass C: append (src,dst) pairs into bucket segments ------------------
__global__ __launch_bounds__(256) void fill_pairs_kernel(
        const int* __restrict__ src, const int* __restrict__ dst, int E,
        int* __restrict__ cur, int2* __restrict__ pairbuf) {
    int e = blockIdx.x * 256 + threadIdx.x;
    if (e >= E) return;
    int s = src[e], d = dst[e];
    int seg = blockIdx.x & 7;
    int pos = atomicAdd(&cur[(((unsigned)d) >> 8) * 8 + seg], 1);
    pairbuf[pos] = make_int2(s, d);
}

// ---- pass D: per-bucket padded CSR build + cursor/pdeg/xd (coalesced) -----
__global__ __launch_bounds__(256) void build_csr_kernel(
        const int2* __restrict__ pairbuf, const int* __restrict__ bnd,
        const int* __restrict__ x, int* __restrict__ cursor,
        int* __restrict__ degcnt, float2* __restrict__ xd,
        int* __restrict__ csr_src, int N) {
    __shared__ int cnt[256], basel[256], curl[256];
    int tid = threadIdx.x;
    int b = blockIdx.x;
    int node0 = b << 8;
    cnt[tid] = 0;
    __syncthreads();
    int bb0 = bnd[b], bb1 = bnd[b + 1];
    for (int i = bb0 + tid; i < bb1; i += 256)
        atomicAdd(&cnt[pairbuf[i].y & 255], 1);
    __syncthreads();
    int c  = cnt[tid];
    int pc = (c + 3) & ~3;              // padded count
    {
        __syncthreads();
        basel[tid] = pc;
        __syncthreads();
        if (tid < 64) {
            int carry = 0;
            for (int cc = 0; cc < 4; ++cc) {
                int orig = basel[cc * 64 + tid];
                int v = orig;
                #pragma unroll
                for (int off = 1; off < 64; off <<= 1) {
                    int t = __shfl_up(v, off);
                    if (tid >= off) v += t;
                }
                int tot = __shfl(v, 63);
                cnt[cc * 64 + tid] = v - orig + carry;   // exclusive
                carry += tot;
            }
        }
        __syncthreads();
    }
    int cb0 = ((bb0 + 3) & ~3) + SLACK * b;   // aligned csr base for bucket
    int node = node0 + tid;
    int myBase = cb0 + cnt[tid];
    curl[tid] = myBase;
    if (node < N) {
        cursor[node] = myBase;
        degcnt[node] = pc;
        xd[node] = make_float2(rsqrtf((float)c + 1.0f), __int_as_float(x[node]));
        for (int t = c; t < pc; ++t) csr_src[myBase + t] = N;   // sentinel pad
    } else if (node == N) {
        xd[N] = make_float2(0.0f, __int_as_float(0));           // zero weight
    }
    __syncthreads();
    for (int i = bb0 + tid; i < bb1; i += 256) {
        int2 p = pairbuf[i];
        int pos = atomicAdd(&curl[p.y & 255], 1);
        csr_src[pos] = p.x;
    }
}

// ---------------- layer 1: agg from embedding table, write g1 = dinv*h1 ----
__global__ __launch_bounds__(256, 8) void layer1_kernel(
        const int* __restrict__ cursor, const int* __restrict__ deg,
        const int* __restrict__ csr_src, const float2* __restrict__ xd,
        const float4* __restrict__ table, const float* __restrict__ W,
        const float* __restrict__ bias, float* __restrict__ g1, int N) {
    __shared__ float Ws[DD * DD];   // 16 KB
    __shared__ float Hs[16 * DD];   // 4 KB
    __shared__ float dvs[16];
    int row0 = blockIdx.x * 16;
    int tid = threadIdx.x;
    {
        const float4* W4 = (const float4*)W;
        float4* Ws4 = (float4*)Ws;
        for (int k = tid; k < DD * DD / 4; k += 256) Ws4[k] = W4[k];
    }
    int node_l = tid >> 4, j = tid & 15;
    int node = row0 + node_l;
    float4 acc0 = make_float4(0.f, 0.f, 0.f, 0.f);
    float4 acc1 = acc0, acc2 = acc0, acc3 = acc0;
    if (node < N) {
        float2 sxd = xd[node];
        float di = sxd.x;
        if (j == 0) dvs[node_l] = di;
        float4 tv = table[(size_t)__float_as_int(sxd.y) * DQ + j];
        acc0.x = di * tv.x; acc0.y = di * tv.y;
        acc0.z = di * tv.z; acc0.w = di * tv.w;
        const int4* cs = (const int4*)(csr_src + cursor[node]);  // 16-B aligned
        int nq = deg[node] >> 2;                                 // padded groups
        for (int q = 0; q < nq; ++q) {
            int4 s4 = cs[q];
            float2 pa = xd[s4.x], pb = xd[s4.y], pc_ = xd[s4.z], pd = xd[s4.w];
            float4 u0 = table[(size_t)__float_as_int(pa.y) * DQ + j];
            float4 u1 = table[(size_t)__float_as_int(pb.y) * DQ + j];
            float4 u2 = table[(size_t)__float_as_int(pc_.y) * DQ + j];
            float4 u3 = table[(size_t)__float_as_int(pd.y) * DQ + j];
            f4fma(acc0, pa.x, u0); f4fma(acc1, pb.x, u1);
            f4fma(acc2, pc_.x, u2); f4fma(acc3, pd.x, u3);
        }
        f4add(acc0, acc1); f4add(acc2, acc3); f4add(acc0, acc2);
        acc0.x *= di; acc0.y *= di; acc0.z *= di; acc0.w *= di;
    }
    ((float4*)Hs)[node_l * DQ + j] = acc0;
    __syncthreads();

    // row-outer MLP (36 VGPR, keeps occupancy for the gather phase)
    int wave = tid >> 6, lane = tid & 63;
    float b = bias[lane];
    #pragma unroll
    for (int rr = 0; rr < 4; ++rr) {
        int row = wave * 4 + rr;
        int grow = row0 + row;
        if (grow >= N) break;
        float a = b;
        #pragma unroll
        for (int k = 0; k < DD; ++k)
            a = fmaf(Hs[row * DD + k], Ws[k * DD + lane], a);
        g1[(size_t)grow * DD + lane] = dvs[row] * fmaxf(a, 0.0f);   // g1 = dinv*h1
    }
}

// -------- layer 2 + pool: agg2 = dinv_v*(g1[v] + sum g1[s]); h2@Wlin pooled --
__global__ __launch_bounds__(256, 8) void layer2_pool_kernel(
        const int* __restrict__ cursor, const int* __restrict__ deg,
        const int* __restrict__ csr_src, const float2* __restrict__ xd,
        const float4* __restrict__ g1, const float* __restrict__ W,
        const float* __restrict__ bias, const int* __restrict__ batch,
        const float* __restrict__ Wlin, float* __restrict__ outacc, int N) {
    __shared__ float Ws[DD * DD];
    __shared__ float Hs[16 * DD];
    __shared__ float p0s[16], p1s[16];
    __shared__ int   bat[16];
    int row0 = blockIdx.x * 16;
    int tid = threadIdx.x;
    {
        const float4* W4 = (const float4*)W;
        float4* Ws4 = (float4*)Ws;
        for (int k = tid; k < DD * DD / 4; k += 256) Ws4[k] = W4[k];
    }
    int node_l = tid >> 4, j = tid & 15;
    int node = row0 + node_l;
    float4 acc0 = make_float4(0.f, 0.f, 0.f, 0.f);
    float4 acc1 = acc0, acc2 = acc0, acc3 = acc0;
    if (node < N) {
        float di = xd[node].x;
        acc0 = g1[(size_t)node * DQ + j];    // self term, weight 1
        const int4* cs = (const int4*)(csr_src + cursor[node]);
        int nq = deg[node] >> 2;
        for (int q = 0; q < nq; ++q) {
            int4 s4 = cs[q];
            float4 u0 = g1[(size_t)s4.x * DQ + j];
            float4 u1 = g1[(size_t)s4.y * DQ + j];
            float4 u2 = g1[(size_t)s4.z * DQ + j];
            float4 u3 = g1[(size_t)s4.w * DQ + j];
            f4add(acc0, u0); f4add(acc1, u1);
            f4add(acc2, u2); f4add(acc3, u3);
        }
        f4add(acc0, acc1); f4add(acc2, acc3); f4add(acc0, acc2);
        acc0.x *= di; acc0.y *= di; acc0.z *= di; acc0.w *= di;
    }
    ((float4*)Hs)[node_l * DQ + j] = acc0;
    __syncthreads();

    int wave = tid >> 6, lane = tid & 63;
    float b   = bias[lane];
    float wl0 = Wlin[lane * 2 + 0];
    float wl1 = Wlin[lane * 2 + 1];
    #pragma unroll
    for (int rr = 0; rr < 4; ++rr) {
        int row = wave * 4 + rr;
        int grow = row0 + row;
        float p0 = 0.f, p1 = 0.f;
        if (grow < N) {
            float a = b;
            #pragma unroll
            for (int k = 0; k < DD; ++k)
                a = fmaf(Hs[row * DD + k], Ws[k * DD + lane], a);
            a = fmaxf(a, 0.0f);
            p0 = a * wl0;
            p1 = a * wl1;
        }
        #pragma unroll
        for (int off = 32; off >= 1; off >>= 1) {
            p0 += __shfl_xor(p0, off);
            p1 += __shfl_xor(p1, off);
        }
        if (lane == 0) {
            p0s[row] = p0;
            p1s[row] = p1;
            bat[row] = (grow < N) ? batch[grow] : -1;
        }
    }
    __syncthreads();
    if (tid < 16) {
        int bg = bat[tid];
        bool head = (bg >= 0) && (tid == 0 || bat[tid - 1] != bg);
        if (head) {
            float s0 = 0.f, s1 = 0.f;
            for (int k = tid; k < 16 && bat[k] == bg; ++k) {
                s0 += p0s[k];
                s1 += p1s[k];
            }
            atomAddF(&outacc[bg * 2 + 0], s0);
            atomAddF(&outacc[bg * 2 + 1], s1);
        }
    }
}

// counts via binary search on sorted batch; then divide + blin
__global__ void final_kernel(const float* __restrict__ outacc,
                             const int* __restrict__ batch,
                             const float* __restrict__ blin,
                             float* __restrict__ out, int G, int N) {
    int t = blockIdx.x * blockDim.x + threadIdx.x;
    if (t >= G * 2) return;
    int g = t >> 1, c = t & 1;
    int lo = 0, hi = N;
    while (lo < hi) { int m = (lo + hi) >> 1; if (batch[m] < g) lo = m + 1; else hi = m; }
    int lo2 = lo, hi2 = N;
    while (lo2 < hi2) { int m = (lo2 + hi2) >> 1; if (batch[m] < g + 1) lo2 = m + 1; else hi2 = m; }
    float cnt = (float)(lo2 - lo);
    out[t] = outacc[t] / fmaxf(cnt, 1.0f) + blin[c];
}

extern "C" void kernel_launch(void* const* d_in, const int* in_sizes, int n_in,
                              void* d_out, int out_size, void* d_ws, size_t ws_size,
                              hipStream_t stream) {
    const int*   x      = (const int*)d_in[0];
    const int*   ei     = (const int*)d_in[1];   // [2,E] row-major
    const int*   batch  = (const int*)d_in[3];
    const float* table  = (const float*)d_in[4];
    const float* W1     = (const float*)d_in[5];
    const float* b1     = (const float*)d_in[6];
    const float* W2     = (const float*)d_in[7];
    const float* b2     = (const float*)d_in[8];
    const float* Wlin   = (const float*)d_in[9];
    const float* blin   = (const float*)d_in[10];
    float* out = (float*)d_out;

    const int N = in_sizes[0];
    const int E = in_sizes[2];          // edge_type count == E
    const int G = out_size / 2;

    const int* src = ei;
    const int* dst = ei + E;

    const int K = (N + BKT - 1) / BKT;  // buckets
    const int M = K * 8;                // (bucket, seg) cells
    const int CSRSZ = E + SLACK * K + 64;

    // workspace layout
    size_t nh = (size_t)N * DD;
    float*  g1      = (float*)d_ws;                 // (N+1)*64 f32
    int2*   pairbuf = (int2*)(g1 + nh + DD);        // E int2
    int*    csr_src = (int*)(pairbuf + E);          // CSRSZ ints
    int*    cursor  = csr_src + CSRSZ;              // N
    int*    degcnt  = cursor + N;                   // N (padded deg)
    float2* xd      = (float2*)(degcnt + N);        // N+1 float2
    int*    hist    = (int*)(xd + N + 1);           // M
    int*    cur     = hist + M;                     // M
    int*    bnd     = cur + M;                      // K+1
    float*  outacc  = (float*)(bnd + K + 2);        // 2G

    const int BT = 256;

    hipMemsetAsync(hist, 0, (size_t)M * sizeof(int), stream);
    hipMemsetAsync(outacc, 0, (size_t)G * 2 * sizeof(float), stream);
    hipMemsetAsync(g1 + nh, 0, DD * sizeof(float), stream);   // zero row N

    // CSR build: histogram -> scan -> bucket append -> per-bucket sort (+pad)
    bin_count_kernel<<<256, BT, 0, stream>>>(dst, E, hist, K);
    scan_kernel<<<1, BT, 0, stream>>>(hist, cur, bnd, M, K, E);
    fill_pairs_kernel<<<(E + BT - 1) / BT, BT, 0, stream>>>(src, dst, E, cur, pairbuf);
    build_csr_kernel<<<K, BT, 0, stream>>>(pairbuf, bnd, x, cursor, degcnt, xd,
                                           csr_src, N);

    // layer 1 (embed+agg+GEMM+relu fused; writes g1 = dinv*h1)
    int gRow = (N + 15) / 16;
    layer1_kernel<<<gRow, BT, 0, stream>>>(cursor, degcnt, csr_src, xd,
                                           (const float4*)table, W1, b1, g1, N);
    // layer 2 (agg+GEMM+relu+pool fused)
    layer2_pool_kernel<<<gRow, BT, 0, stream>>>(cursor, degcnt, csr_src, xd,
                                                (const float4*)g1, W2, b2,
                                                batch, Wlin, outacc, N);
    // final
    final_kernel<<<(G * 2 + BT - 1) / BT, BT, 0, stream>>>(outacc, batch, blin,
                                                           out, G, N);
}

// Round 8
// 395.743 us; speedup vs baseline: 2.3056x; 1.1263x over previous
//
#include <hip/hip_runtime.h>

// ---------------------------------------------------------------------------
// GCN forward on MI355X — round 8.
//  * Ws evicted from LDS: MLP reads W straight from global (L1-hot broadcast,
//    lane l only ever touches column l). LDS/block 20992 -> ~4.3 KB, so
//    blocks/CU 5 -> 8 and the latency-bound gather gets ~100% occupancy.
//  * MLP k-outer with scalar Hs LDS broadcasts (4 accs + 1 w live -> low VGPR).
//  * Gather loop unchanged from round 7 (padded branchless int4, sentinel N).
// ---------------------------------------------------------------------------

#define DD 64          // feature dim
#define DQ 16          // float4s per row
#define BKT 256        // nodes per bucket
#define MAXK 1024      // max buckets (N <= 262144)
#define SLACK 772      // per-bucket csr slack: 3*256 pad + 4 alignment

static __device__ __forceinline__ void atomAddF(float* p, float v) {
    unsafeAtomicAdd(p, v);   // global_atomic_add_f32 on gfx950
}

static __device__ __forceinline__ void f4fma(float4& a, float w, const float4& u) {
    a.x = fmaf(w, u.x, a.x); a.y = fmaf(w, u.y, a.y);
    a.z = fmaf(w, u.z, a.z); a.w = fmaf(w, u.w, a.w);
}
static __device__ __forceinline__ void f4add(float4& a, const float4& u) {
    a.x += u.x; a.y += u.y; a.z += u.z; a.w += u.w;
}

// ---- pass A: bucket histogram, segmented by blockIdx&7 (~XCD) -------------
__global__ __launch_bounds__(256) void bin_count_kernel(
        const int* __restrict__ dst, int E, int* __restrict__ hist, int K) {
    __shared__ int lh[MAXK];
    int tid = threadIdx.x;
    for (int i = tid; i < K; i += 256) lh[i] = 0;
    __syncthreads();
    int stride = gridDim.x * 256;
    for (int e = blockIdx.x * 256 + tid; e < E; e += stride)
        atomicAdd(&lh[((unsigned)dst[e]) >> 8], 1);
    __syncthreads();
    int seg = blockIdx.x & 7;
    for (int b = tid; b < K; b += 256) {
        int c = lh[b];
        if (c) atomicAdd(&hist[b * 8 + seg], c);
    }
}

// ---- pass B: exclusive scan of hist[M] -> cur (append cursors) + bnd ------
__global__ __launch_bounds__(256) void scan_kernel(
        const int* __restrict__ hist, int* __restrict__ cur,
        int* __restrict__ bnd, int M, int K, int E) {
    __shared__ int part[256];
    int tid = threadIdx.x;
    int CH = (M + 255) / 256;
    int base = tid * CH;
    int s = 0;
    for (int i = 0; i < CH; ++i) {
        int idx = base + i;
        if (idx < M) s += hist[idx];
    }
    part[tid] = s;
    __syncthreads();
    if (tid < 64) {
        int carry = 0;
        for (int c = 0; c < 4; ++c) {
            int orig = part[c * 64 + tid];
            int v = orig;
            #pragma unroll
            for (int off = 1; off < 64; off <<= 1) {
                int t = __shfl_up(v, off);
                if (tid >= off) v += t;
            }
            int tot = __shfl(v, 63);
            part[c * 64 + tid] = v - orig + carry;   // exclusive
            carry += tot;
        }
    }
    __syncthreads();
    int run = part[tid];
    for (int i = 0; i < CH; ++i) {
        int idx = base + i;
        if (idx < M) {
            cur[idx] = run;
            if ((idx & 7) == 0) bnd[idx >> 3] = run;
            run += hist[idx];
        }
    }
    if (tid == 0) bnd[K] = E;
}

// ---- pass C: append (src,dst) pairs into bucket segments ------------------
__global__ __launch_bounds__(256) void fill_pairs_kernel(
        const int* __restrict__ src, const int* __restrict__ dst, int E,
        int* __restrict__ cur, int2* __restrict__ pairbuf) {
    int e = blockIdx.x * 256 + threadIdx.x;
    if (e >= E) return;
    int s = src[e], d = dst[e];
    int seg = blockIdx.x & 7;
    int pos = atomicAdd(&cur[(((unsigned)d) >> 8) * 8 + seg], 1);
    pairbuf[pos] = make_int2(s, d);
}

// ---- pass D: per-bucket padded CSR build + cursor/pdeg/xd (coalesced) -----
__global__ __launch_bounds__(256) void build_csr_kernel(
        const int2* __restrict__ pairbuf, const int* __restrict__ bnd,
        const int* __restrict__ x, int* __restrict__ cursor,
        int* __restrict__ degcnt, float2* __restrict__ xd,
        int* __restrict__ csr_src, int N) {
    __shared__ int cnt[256], basel[256], curl[256];
    int tid = threadIdx.x;
    int b = blockIdx.x;
    int node0 = b << 8;
    cnt[tid] = 0;
    __syncthreads();
    int bb0 = bnd[b], bb1 = bnd[b + 1];
    for (int i = bb0 + tid; i < bb1; i += 256)
        atomicAdd(&cnt[pairbuf[i].y & 255], 1);
    __syncthreads();
    int c  = cnt[tid];
    int pc = (c + 3) & ~3;              // padded count
    {
        __syncthreads();
        basel[tid] = pc;
        __syncthreads();
        if (tid < 64) {
            int carry = 0;
            for (int cc = 0; cc < 4; ++cc) {
                int orig = basel[cc * 64 + tid];
                int v = orig;
                #pragma unroll
                for (int off = 1; off < 64; off <<= 1) {
                    int t = __shfl_up(v, off);
                    if (tid >= off) v += t;
                }
                int tot = __shfl(v, 63);
                cnt[cc * 64 + tid] = v - orig + carry;   // exclusive
                carry += tot;
            }
        }
        __syncthreads();
    }
    int cb0 = ((bb0 + 3) & ~3) + SLACK * b;   // aligned csr base for bucket
    int node = node0 + tid;
    int myBase = cb0 + cnt[tid];
    curl[tid] = myBase;
    if (node < N) {
        cursor[node] = myBase;
        degcnt[node] = pc;
        xd[node] = make_float2(rsqrtf((float)c + 1.0f), __int_as_float(x[node]));
        for (int t = c; t < pc; ++t) csr_src[myBase + t] = N;   // sentinel pad
    } else if (node == N) {
        xd[N] = make_float2(0.0f, __int_as_float(0));           // zero weight
    }
    __syncthreads();
    for (int i = bb0 + tid; i < bb1; i += 256) {
        int2 p = pairbuf[i];
        int pos = atomicAdd(&curl[p.y & 255], 1);
        csr_src[pos] = p.x;
    }
}

// ---------------- layer 1: agg from embedding table, write g1 = dinv*h1 ----
__global__ __launch_bounds__(256, 8) void layer1_kernel(
        const int* __restrict__ cursor, const int* __restrict__ deg,
        const int* __restrict__ csr_src, const float2* __restrict__ xd,
        const float4* __restrict__ table, const float* __restrict__ W,
        const float* __restrict__ bias, float* __restrict__ g1, int N) {
    __shared__ float Hs[16 * DD];   // 4 KB
    __shared__ float dvs[16];
    int row0 = blockIdx.x * 16;
    int tid = threadIdx.x;
    int node_l = tid >> 4, j = tid & 15;
    int node = row0 + node_l;
    float4 acc0 = make_float4(0.f, 0.f, 0.f, 0.f);
    float4 acc1 = acc0, acc2 = acc0, acc3 = acc0;
    if (node < N) {
        float2 sxd = xd[node];
        float di = sxd.x;
        if (j == 0) dvs[node_l] = di;
        float4 tv = table[(size_t)__float_as_int(sxd.y) * DQ + j];
        acc0.x = di * tv.x; acc0.y = di * tv.y;
        acc0.z = di * tv.z; acc0.w = di * tv.w;
        const int4* cs = (const int4*)(csr_src + cursor[node]);  // 16-B aligned
        int nq = deg[node] >> 2;                                 // padded groups
        for (int q = 0; q < nq; ++q) {
            int4 s4 = cs[q];
            float2 pa = xd[s4.x], pb = xd[s4.y], pc_ = xd[s4.z], pd = xd[s4.w];
            float4 u0 = table[(size_t)__float_as_int(pa.y) * DQ + j];
            float4 u1 = table[(size_t)__float_as_int(pb.y) * DQ + j];
            float4 u2 = table[(size_t)__float_as_int(pc_.y) * DQ + j];
            float4 u3 = table[(size_t)__float_as_int(pd.y) * DQ + j];
            f4fma(acc0, pa.x, u0); f4fma(acc1, pb.x, u1);
            f4fma(acc2, pc_.x, u2); f4fma(acc3, pd.x, u3);
        }
        f4add(acc0, acc1); f4add(acc2, acc3); f4add(acc0, acc2);
        acc0.x *= di; acc0.y *= di; acc0.z *= di; acc0.w *= di;
    }
    ((float4*)Hs)[node_l * DQ + j] = acc0;
    __syncthreads();

    // MLP: W column `lane` from global (L1-hot), Hs via LDS scalar broadcasts.
    int wave = tid >> 6, lane = tid & 63;
    int rbase = wave * 4;
    float bb = bias[lane];
    float A0 = bb, A1 = bb, A2 = bb, A3 = bb;
    #pragma unroll 8
    for (int k = 0; k < DD; ++k) {
        float w  = W[k * DD + lane];
        float h0 = Hs[(rbase + 0) * DD + k];
        float h1 = Hs[(rbase + 1) * DD + k];
        float h2 = Hs[(rbase + 2) * DD + k];
        float h3 = Hs[(rbase + 3) * DD + k];
        A0 = fmaf(h0, w, A0); A1 = fmaf(h1, w, A1);
        A2 = fmaf(h2, w, A2); A3 = fmaf(h3, w, A3);
    }
    if (row0 + rbase + 0 < N) g1[(size_t)(row0 + rbase + 0) * DD + lane] = dvs[rbase + 0] * fmaxf(A0, 0.0f);
    if (row0 + rbase + 1 < N) g1[(size_t)(row0 + rbase + 1) * DD + lane] = dvs[rbase + 1] * fmaxf(A1, 0.0f);
    if (row0 + rbase + 2 < N) g1[(size_t)(row0 + rbase + 2) * DD + lane] = dvs[rbase + 2] * fmaxf(A2, 0.0f);
    if (row0 + rbase + 3 < N) g1[(size_t)(row0 + rbase + 3) * DD + lane] = dvs[rbase + 3] * fmaxf(A3, 0.0f);
}

// -------- layer 2 + pool: agg2 = dinv_v*(g1[v] + sum g1[s]); h2@Wlin pooled --
__global__ __launch_bounds__(256, 8) void layer2_pool_kernel(
        const int* __restrict__ cursor, const int* __restrict__ deg,
        const int* __restrict__ csr_src, const float2* __restrict__ xd,
        const float4* __restrict__ g1, const float* __restrict__ W,
        const float* __restrict__ bias, const int* __restrict__ batch,
        const float* __restrict__ Wlin, float* __restrict__ outacc, int N) {
    __shared__ float Hs[16 * DD];   // 4 KB
    __shared__ float p0s[16], p1s[16];
    __shared__ int   bat[16];
    int row0 = blockIdx.x * 16;
    int tid = threadIdx.x;
    int node_l = tid >> 4, j = tid & 15;
    int node = row0 + node_l;
    float4 acc0 = make_float4(0.f, 0.f, 0.f, 0.f);
    float4 acc1 = acc0, acc2 = acc0, acc3 = acc0;
    if (node < N) {
        float di = xd[node].x;
        acc0 = g1[(size_t)node * DQ + j];    // self term, weight 1
        const int4* cs = (const int4*)(csr_src + cursor[node]);
        int nq = deg[node] >> 2;
        for (int q = 0; q < nq; ++q) {
            int4 s4 = cs[q];
            float4 u0 = g1[(size_t)s4.x * DQ + j];
            float4 u1 = g1[(size_t)s4.y * DQ + j];
            float4 u2 = g1[(size_t)s4.z * DQ + j];
            float4 u3 = g1[(size_t)s4.w * DQ + j];
            f4add(acc0, u0); f4add(acc1, u1);
            f4add(acc2, u2); f4add(acc3, u3);
        }
        f4add(acc0, acc1); f4add(acc2, acc3); f4add(acc0, acc2);
        acc0.x *= di; acc0.y *= di; acc0.z *= di; acc0.w *= di;
    }
    ((float4*)Hs)[node_l * DQ + j] = acc0;
    __syncthreads();

    int wave = tid >> 6, lane = tid & 63;
    int rbase = wave * 4;
    float bb = bias[lane];
    float A0 = bb, A1 = bb, A2 = bb, A3 = bb;
    #pragma unroll 8
    for (int k = 0; k < DD; ++k) {
        float w  = W[k * DD + lane];
        float h0 = Hs[(rbase + 0) * DD + k];
        float h1 = Hs[(rbase + 1) * DD + k];
        float h2 = Hs[(rbase + 2) * DD + k];
        float h3 = Hs[(rbase + 3) * DD + k];
        A0 = fmaf(h0, w, A0); A1 = fmaf(h1, w, A1);
        A2 = fmaf(h2, w, A2); A3 = fmaf(h3, w, A3);
    }
    float wl0 = Wlin[lane * 2 + 0];
    float wl1 = Wlin[lane * 2 + 1];
    float Ar[4] = {A0, A1, A2, A3};
    #pragma unroll
    for (int rr = 0; rr < 4; ++rr) {
        int row = rbase + rr;
        int grow = row0 + row;
        float a = fmaxf(Ar[rr], 0.0f);
        float p0 = (grow < N) ? a * wl0 : 0.f;
        float p1 = (grow < N) ? a * wl1 : 0.f;
        #pragma unroll
        for (int off = 32; off >= 1; off >>= 1) {
            p0 += __shfl_xor(p0, off);
            p1 += __shfl_xor(p1, off);
        }
        if (lane == 0) {
            p0s[row] = p0;
            p1s[row] = p1;
            bat[row] = (grow < N) ? batch[grow] : -1;
        }
    }
    __syncthreads();
    if (tid < 16) {
        int bg = bat[tid];
        bool head = (bg >= 0) && (tid == 0 || bat[tid - 1] != bg);
        if (head) {
            float s0 = 0.f, s1 = 0.f;
            for (int k = tid; k < 16 && bat[k] == bg; ++k) {
                s0 += p0s[k];
                s1 += p1s[k];
            }
            atomAddF(&outacc[bg * 2 + 0], s0);
            atomAddF(&outacc[bg * 2 + 1], s1);
        }
    }
}

// counts via binary search on sorted batch; then divide + blin
__global__ void final_kernel(const float* __restrict__ outacc,
                             const int* __restrict__ batch,
                             const float* __restrict__ blin,
                             float* __restrict__ out, int G, int N) {
    int t = blockIdx.x * blockDim.x + threadIdx.x;
    if (t >= G * 2) return;
    int g = t >> 1, c = t & 1;
    int lo = 0, hi = N;
    while (lo < hi) { int m = (lo + hi) >> 1; if (batch[m] < g) lo = m + 1; else hi = m; }
    int lo2 = lo, hi2 = N;
    while (lo2 < hi2) { int m = (lo2 + hi2) >> 1; if (batch[m] < g + 1) lo2 = m + 1; else hi2 = m; }
    float cnt = (float)(lo2 - lo);
    out[t] = outacc[t] / fmaxf(cnt, 1.0f) + blin[c];
}

extern "C" void kernel_launch(void* const* d_in, const int* in_sizes, int n_in,
                              void* d_out, int out_size, void* d_ws, size_t ws_size,
                              hipStream_t stream) {
    const int*   x      = (const int*)d_in[0];
    const int*   ei     = (const int*)d_in[1];   // [2,E] row-major
    const int*   batch  = (const int*)d_in[3];
    const float* table  = (const float*)d_in[4];
    const float* W1     = (const float*)d_in[5];
    const float* b1     = (const float*)d_in[6];
    const float* W2     = (const float*)d_in[7];
    const float* b2     = (const float*)d_in[8];
    const float* Wlin   = (const float*)d_in[9];
    const float* blin   = (const float*)d_in[10];
    float* out = (float*)d_out;

    const int N = in_sizes[0];
    const int E = in_sizes[2];          // edge_type count == E
    const int G = out_size / 2;

    const int* src = ei;
    const int* dst = ei + E;

    const int K = (N + BKT - 1) / BKT;  // buckets
    const int M = K * 8;                // (bucket, seg) cells
    const int CSRSZ = E + SLACK * K + 64;

    // workspace layout
    size_t nh = (size_t)N * DD;
    float*  g1      = (float*)d_ws;                 // (N+1)*64 f32
    int2*   pairbuf = (int2*)(g1 + nh + DD);        // E int2
    int*    csr_src = (int*)(pairbuf + E);          // CSRSZ ints
    int*    cursor  = csr_src + CSRSZ;              // N
    int*    degcnt  = cursor + N;                   // N (padded deg)
    float2* xd      = (float2*)(degcnt + N);        // N+1 float2
    int*    hist    = (int*)(xd + N + 1);           // M
    int*    cur     = hist + M;                     // M
    int*    bnd     = cur + M;                      // K+1
    float*  outacc  = (float*)(bnd + K + 2);        // 2G

    const int BT = 256;

    hipMemsetAsync(hist, 0, (size_t)M * sizeof(int), stream);
    hipMemsetAsync(outacc, 0, (size_t)G * 2 * sizeof(float), stream);
    hipMemsetAsync(g1 + nh, 0, DD * sizeof(float), stream);   // zero row N

    // CSR build: histogram -> scan -> bucket append -> per-bucket sort (+pad)
    bin_count_kernel<<<256, BT, 0, stream>>>(dst, E, hist, K);
    scan_kernel<<<1, BT, 0, stream>>>(hist, cur, bnd, M, K, E);
    fill_pairs_kernel<<<(E + BT - 1) / BT, BT, 0, stream>>>(src, dst, E, cur, pairbuf);
    build_csr_kernel<<<K, BT, 0, stream>>>(pairbuf, bnd, x, cursor, degcnt, xd,
                                           csr_src, N);

    // layer 1 (embed+agg+GEMM+relu fused; writes g1 = dinv*h1)
    int gRow = (N + 15) / 16;
    layer1_kernel<<<gRow, BT, 0, stream>>>(cursor, degcnt, csr_src, xd,
                                           (const float4*)table, W1, b1, g1, N);
    // layer 2 (agg+GEMM+relu+pool fused)
    layer2_pool_kernel<<<gRow, BT, 0, stream>>>(cursor, degcnt, csr_src, xd,
                                                (const float4*)g1, W2, b2,
                                                batch, Wlin, outacc, N);
    // final
    final_kernel<<<(G * 2 + BT - 1) / BT, BT, 0, stream>>>(outacc, batch, blin,
                                                           out, G, N);
}

// Round 9
// 373.183 us; speedup vs baseline: 2.4450x; 1.0605x over previous
//
#include <hip/hip_runtime.h>
#include <hip/hip_fp16.h>

// ---------------------------------------------------------------------------
// GCN forward on MI355X — round 9.
//  * fp16 feature storage: g1 (layer1 output) and the embedding table are
//    half-precision -> gather rows are 128B not 256B (half the random-read
//    bytes) and accumulate via v_pk_add/fma_f16 (half the gather VALU ops).
//    Error analysis: ~1e-7 at output vs 6.9e-5 threshold (~500x margin).
//  * pairbuf packed to one int (s | (d&255)<<24; N < 2^24).
//  * single memset (hist+outacc adjacent); g1h sentinel row zeroed in
//    build_csr.  MLP keeps f32 (W read from global, L1-hot; round 8).
// ---------------------------------------------------------------------------

#define DD 64          // feature dim
#define DQ 16          // float4s per row
#define BKT 256        // nodes per bucket
#define MAXK 1024      // max buckets (N <= 262144)
#define SLACK 772      // per-bucket csr slack: 3*256 pad + 4 alignment

static __device__ __forceinline__ void atomAddF(float* p, float v) {
    unsafeAtomicAdd(p, v);   // global_atomic_add_f32 on gfx950
}

// load 4 halves (8B) as two __half2
static __device__ __forceinline__ void h4load(const __half* base, size_t idx8,
                                              __half2& lo, __half2& hi) {
    float2 raw = ((const float2*)base)[idx8];
    lo = *(__half2*)&raw.x;
    hi = *(__half2*)&raw.y;
}

// ---- pass A: bucket histogram (+ fp16 table conversion piggy-backed) ------
__global__ __launch_bounds__(256) void bin_count_kernel(
        const int* __restrict__ dst, int E, int* __restrict__ hist, int K,
        const float2* __restrict__ table2, __half2* __restrict__ th2, int n2) {
    __shared__ int lh[MAXK];
    int tid = threadIdx.x;
    for (int i = tid; i < K; i += 256) lh[i] = 0;
    __syncthreads();
    int stride = gridDim.x * 256;
    for (int i = blockIdx.x * 256 + tid; i < n2; i += stride)
        th2[i] = __float22half2_rn(table2[i]);
    for (int e = blockIdx.x * 256 + tid; e < E; e += stride)
        atomicAdd(&lh[((unsigned)dst[e]) >> 8], 1);
    __syncthreads();
    int seg = blockIdx.x & 7;
    for (int b = tid; b < K; b += 256) {
        int c = lh[b];
        if (c) atomicAdd(&hist[b * 8 + seg], c);
    }
}

// ---- pass B: exclusive scan of hist[M] -> cur (append cursors) + bnd ------
__global__ __launch_bounds__(256) void scan_kernel(
        const int* __restrict__ hist, int* __restrict__ cur,
        int* __restrict__ bnd, int M, int K, int E) {
    __shared__ int part[256];
    int tid = threadIdx.x;
    int CH = (M + 255) / 256;
    int base = tid * CH;
    int s = 0;
    for (int i = 0; i < CH; ++i) {
        int idx = base + i;
        if (idx < M) s += hist[idx];
    }
    part[tid] = s;
    __syncthreads();
    if (tid < 64) {
        int carry = 0;
        for (int c = 0; c < 4; ++c) {
            int orig = part[c * 64 + tid];
            int v = orig;
            #pragma unroll
            for (int off = 1; off < 64; off <<= 1) {
                int t = __shfl_up(v, off);
                if (tid >= off) v += t;
            }
            int tot = __shfl(v, 63);
            part[c * 64 + tid] = v - orig + carry;   // exclusive
            carry += tot;
        }
    }
    __syncthreads();
    int run = part[tid];
    for (int i = 0; i < CH; ++i) {
        int idx = base + i;
        if (idx < M) {
            cur[idx] = run;
            if ((idx & 7) == 0) bnd[idx >> 3] = run;
            run += hist[idx];
        }
    }
    if (tid == 0) bnd[K] = E;
}

// ---- pass C: append packed (src | (dst&255)<<24) into bucket segments -----
__global__ __launch_bounds__(256) void fill_pairs_kernel(
        const int* __restrict__ src, const int* __restrict__ dst, int E,
        int* __restrict__ cur, int* __restrict__ pairbuf) {
    int e = blockIdx.x * 256 + threadIdx.x;
    if (e >= E) return;
    int s = src[e], d = dst[e];
    int seg = blockIdx.x & 7;
    int pos = atomicAdd(&cur[(((unsigned)d) >> 8) * 8 + seg], 1);
    pairbuf[pos] = s | ((d & 255) << 24);
}

// ---- pass D: per-bucket padded CSR build + cursor/pdeg/xd (coalesced) -----
__global__ __launch_bounds__(256) void build_csr_kernel(
        const int* __restrict__ pairbuf, const int* __restrict__ bnd,
        const int* __restrict__ x, int* __restrict__ cursor,
        int* __restrict__ degcnt, float2* __restrict__ xd,
        int* __restrict__ csr_src, __half* __restrict__ g1h, int N) {
    __shared__ int cnt[256], basel[256], curl[256];
    int tid = threadIdx.x;
    int b = blockIdx.x;
    int node0 = b << 8;
    cnt[tid] = 0;
    __syncthreads();
    int bb0 = bnd[b], bb1 = bnd[b + 1];
    for (int i = bb0 + tid; i < bb1; i += 256)
        atomicAdd(&cnt[((unsigned)pairbuf[i]) >> 24], 1);
    __syncthreads();
    int c  = cnt[tid];
    int pc = (c + 3) & ~3;              // padded count
    {
        __syncthreads();
        basel[tid] = pc;
        __syncthreads();
        if (tid < 64) {
            int carry = 0;
            for (int cc = 0; cc < 4; ++cc) {
                int orig = basel[cc * 64 + tid];
                int v = orig;
                #pragma unroll
                for (int off = 1; off < 64; off <<= 1) {
                    int t = __shfl_up(v, off);
                    if (tid >= off) v += t;
                }
                int tot = __shfl(v, 63);
                cnt[cc * 64 + tid] = v - orig + carry;   // exclusive
                carry += tot;
            }
        }
        __syncthreads();
    }
    int cb0 = ((bb0 + 3) & ~3) + SLACK * b;   // aligned csr base for bucket
    int node = node0 + tid;
    int myBase = cb0 + cnt[tid];
    curl[tid] = myBase;
    if (node < N) {
        cursor[node] = myBase;
        degcnt[node] = pc;
        xd[node] = make_float2(rsqrtf((float)c + 1.0f), __int_as_float(x[node]));
        for (int t = c; t < pc; ++t) csr_src[myBase + t] = N;   // sentinel pad
    } else if (node == N) {
        xd[N] = make_float2(0.0f, __int_as_float(0));           // zero weight
        float2* z = (float2*)(g1h + (size_t)N * DD);            // zero row N
        for (int t = 0; t < DD / 4; ++t) z[t] = make_float2(0.f, 0.f);
    }
    __syncthreads();
    for (int i = bb0 + tid; i < bb1; i += 256) {
        int pk = pairbuf[i];
        int pos = atomicAdd(&curl[((unsigned)pk) >> 24], 1);
        csr_src[pos] = pk & 0x00FFFFFF;
    }
}

// ---------------- layer 1: agg from fp16 table, write g1h = fp16(dinv*h1) ---
__global__ __launch_bounds__(256, 8) void layer1_kernel(
        const int* __restrict__ cursor, const int* __restrict__ deg,
        const int* __restrict__ csr_src, const float2* __restrict__ xd,
        const __half* __restrict__ th, const float* __restrict__ W,
        const float* __restrict__ bias, __half* __restrict__ g1h, int N) {
    __shared__ float Hs[16 * DD];   // 4 KB
    __shared__ float dvs[16];
    int row0 = blockIdx.x * 16;
    int tid = threadIdx.x;
    int node_l = tid >> 4, j = tid & 15;
    int node = row0 + node_l;
    __half2 z = __float2half2_rn(0.f);
    __half2 aL0 = z, aL1 = z, aL2 = z, aL3 = z;
    __half2 aH0 = z, aH1 = z, aH2 = z, aH3 = z;
    float di = 0.f;
    if (node < N) {
        float2 sxd = xd[node];
        di = sxd.x;
        if (j == 0) dvs[node_l] = di;
        // self term: di * t[x_v]
        __half2 dh = __float2half2_rn(di);
        __half2 lo, hi;
        h4load(th, (size_t)__float_as_int(sxd.y) * DQ + j, lo, hi);
        aL0 = __hmul2(dh, lo);
        aH0 = __hmul2(dh, hi);
        const int4* cs = (const int4*)(csr_src + cursor[node]);  // 16-B aligned
        int nq = deg[node] >> 2;                                 // padded groups
        for (int q = 0; q < nq; ++q) {
            int4 s4 = cs[q];
            float2 pa = xd[s4.x], pb = xd[s4.y], pc_ = xd[s4.z], pd = xd[s4.w];
            __half2 w0 = __float2half2_rn(pa.x);
            __half2 w1 = __float2half2_rn(pb.x);
            __half2 w2 = __float2half2_rn(pc_.x);
            __half2 w3 = __float2half2_rn(pd.x);
            __half2 l0, h0, l1, h1, l2, h2, l3, h3;
            h4load(th, (size_t)__float_as_int(pa.y)  * DQ + j, l0, h0);
            h4load(th, (size_t)__float_as_int(pb.y)  * DQ + j, l1, h1);
            h4load(th, (size_t)__float_as_int(pc_.y) * DQ + j, l2, h2);
            h4load(th, (size_t)__float_as_int(pd.y)  * DQ + j, l3, h3);
            aL0 = __hfma2(w0, l0, aL0); aH0 = __hfma2(w0, h0, aH0);
            aL1 = __hfma2(w1, l1, aL1); aH1 = __hfma2(w1, h1, aH1);
            aL2 = __hfma2(w2, l2, aL2); aH2 = __hfma2(w2, h2, aH2);
            aL3 = __hfma2(w3, l3, aL3); aH3 = __hfma2(w3, h3, aH3);
        }
    }
    aL0 = __hadd2(__hadd2(aL0, aL1), __hadd2(aL2, aL3));
    aH0 = __hadd2(__hadd2(aH0, aH1), __hadd2(aH2, aH3));
    float2 fl = __half22float2(aL0);
    float2 fh = __half22float2(aH0);
    float4 acc = make_float4(fl.x * di, fl.y * di, fh.x * di, fh.y * di);
    ((float4*)Hs)[node_l * DQ + j] = acc;
    __syncthreads();

    // MLP f32: W column `lane` from global (L1-hot), Hs via LDS broadcasts.
    int wave = tid >> 6, lane = tid & 63;
    int rbase = wave * 4;
    float bb = bias[lane];
    float A0 = bb, A1 = bb, A2 = bb, A3 = bb;
    #pragma unroll 8
    for (int k = 0; k < DD; ++k) {
        float w  = W[k * DD + lane];
        float h0 = Hs[(rbase + 0) * DD + k];
        float h1 = Hs[(rbase + 1) * DD + k];
        float h2 = Hs[(rbase + 2) * DD + k];
        float h3 = Hs[(rbase + 3) * DD + k];
        A0 = fmaf(h0, w, A0); A1 = fmaf(h1, w, A1);
        A2 = fmaf(h2, w, A2); A3 = fmaf(h3, w, A3);
    }
    if (row0 + rbase + 0 < N) g1h[(size_t)(row0 + rbase + 0) * DD + lane] = __float2half(dvs[rbase + 0] * fmaxf(A0, 0.0f));
    if (row0 + rbase + 1 < N) g1h[(size_t)(row0 + rbase + 1) * DD + lane] = __float2half(dvs[rbase + 1] * fmaxf(A1, 0.0f));
    if (row0 + rbase + 2 < N) g1h[(size_t)(row0 + rbase + 2) * DD + lane] = __float2half(dvs[rbase + 2] * fmaxf(A2, 0.0f));
    if (row0 + rbase + 3 < N) g1h[(size_t)(row0 + rbase + 3) * DD + lane] = __float2half(dvs[rbase + 3] * fmaxf(A3, 0.0f));
}

// -------- layer 2 + pool: agg2 = dinv_v*(g1[v] + sum g1[s]); h2@Wlin pooled --
__global__ __launch_bounds__(256, 8) void layer2_pool_kernel(
        const int* __restrict__ cursor, const int* __restrict__ deg,
        const int* __restrict__ csr_src, const float2* __restrict__ xd,
        const __half* __restrict__ g1h, const float* __restrict__ W,
        const float* __restrict__ bias, const int* __restrict__ batch,
        const float* __restrict__ Wlin, float* __restrict__ outacc, int N) {
    __shared__ float Hs[16 * DD];   // 4 KB
    __shared__ float p0s[16], p1s[16];
    __shared__ int   bat[16];
    int row0 = blockIdx.x * 16;
    int tid = threadIdx.x;
    int node_l = tid >> 4, j = tid & 15;
    int node = row0 + node_l;
    __half2 z = __float2half2_rn(0.f);
    __half2 aL0 = z, aL1 = z, aL2 = z, aL3 = z;
    __half2 aH0 = z, aH1 = z, aH2 = z, aH3 = z;
    float di = 0.f;
    if (node < N) {
        di = xd[node].x;
        h4load(g1h, (size_t)node * DQ + j, aL0, aH0);   // self term, weight 1
        const int4* cs = (const int4*)(csr_src + cursor[node]);
        int nq = deg[node] >> 2;
        for (int q = 0; q < nq; ++q) {
            int4 s4 = cs[q];
            __half2 l0, h0, l1, h1, l2, h2, l3, h3;
            h4load(g1h, (size_t)s4.x * DQ + j, l0, h0);
            h4load(g1h, (size_t)s4.y * DQ + j, l1, h1);
            h4load(g1h, (size_t)s4.z * DQ + j, l2, h2);
            h4load(g1h, (size_t)s4.w * DQ + j, l3, h3);
            aL0 = __hadd2(aL0, l0); aH0 = __hadd2(aH0, h0);
            aL1 = __hadd2(aL1, l1); aH1 = __hadd2(aH1, h1);
            aL2 = __hadd2(aL2, l2); aH2 = __hadd2(aH2, h2);
            aL3 = __hadd2(aL3, l3); aH3 = __hadd2(aH3, h3);
        }
    }
    aL0 = __hadd2(__hadd2(aL0, aL1), __hadd2(aL2, aL3));
    aH0 = __hadd2(__hadd2(aH0, aH1), __hadd2(aH2, aH3));
    float2 fl = __half22float2(aL0);
    float2 fh = __half22float2(aH0);
    ((float4*)Hs)[node_l * DQ + j] =
        make_float4(fl.x * di, fl.y * di, fh.x * di, fh.y * di);
    __syncthreads();

    int wave = tid >> 6, lane = tid & 63;
    int rbase = wave * 4;
    float bb = bias[lane];
    float A0 = bb, A1 = bb, A2 = bb, A3 = bb;
    #pragma unroll 8
    for (int k = 0; k < DD; ++k) {
        float w  = W[k * DD + lane];
        float h0 = Hs[(rbase + 0) * DD + k];
        float h1 = Hs[(rbase + 1) * DD + k];
        float h2 = Hs[(rbase + 2) * DD + k];
        float h3 = Hs[(rbase + 3) * DD + k];
        A0 = fmaf(h0, w, A0); A1 = fmaf(h1, w, A1);
        A2 = fmaf(h2, w, A2); A3 = fmaf(h3, w, A3);
    }
    float wl0 = Wlin[lane * 2 + 0];
    float wl1 = Wlin[lane * 2 + 1];
    float Ar[4] = {A0, A1, A2, A3};
    #pragma unroll
    for (int rr = 0; rr < 4; ++rr) {
        int row = rbase + rr;
        int grow = row0 + row;
        float a = fmaxf(Ar[rr], 0.0f);
        float p0 = (grow < N) ? a * wl0 : 0.f;
        float p1 = (grow < N) ? a * wl1 : 0.f;
        #pragma unroll
        for (int off = 32; off >= 1; off >>= 1) {
            p0 += __shfl_xor(p0, off);
            p1 += __shfl_xor(p1, off);
        }
        if (lane == 0) {
            p0s[row] = p0;
            p1s[row] = p1;
            bat[row] = (grow < N) ? batch[grow] : -1;
        }
    }
    __syncthreads();
    if (tid < 16) {
        int bg = bat[tid];
        bool head = (bg >= 0) && (tid == 0 || bat[tid - 1] != bg);
        if (head) {
            float s0 = 0.f, s1 = 0.f;
            for (int k = tid; k < 16 && bat[k] == bg; ++k) {
                s0 += p0s[k];
                s1 += p1s[k];
            }
            atomAddF(&outacc[bg * 2 + 0], s0);
            atomAddF(&outacc[bg * 2 + 1], s1);
        }
    }
}

// counts via binary search on sorted batch; then divide + blin
__global__ void final_kernel(const float* __restrict__ outacc,
                             const int* __restrict__ batch,
                             const float* __restrict__ blin,
                             float* __restrict__ out, int G, int N) {
    int t = blockIdx.x * blockDim.x + threadIdx.x;
    if (t >= G * 2) return;
    int g = t >> 1, c = t & 1;
    int lo = 0, hi = N;
    while (lo < hi) { int m = (lo + hi) >> 1; if (batch[m] < g) lo = m + 1; else hi = m; }
    int lo2 = lo, hi2 = N;
    while (lo2 < hi2) { int m = (lo2 + hi2) >> 1; if (batch[m] < g + 1) lo2 = m + 1; else hi2 = m; }
    float cnt = (float)(lo2 - lo);
    out[t] = outacc[t] / fmaxf(cnt, 1.0f) + blin[c];
}

extern "C" void kernel_launch(void* const* d_in, const int* in_sizes, int n_in,
                              void* d_out, int out_size, void* d_ws, size_t ws_size,
                              hipStream_t stream) {
    const int*   x      = (const int*)d_in[0];
    const int*   ei     = (const int*)d_in[1];   // [2,E] row-major
    const int*   batch  = (const int*)d_in[3];
    const float* table  = (const float*)d_in[4];
    const float* W1     = (const float*)d_in[5];
    const float* b1     = (const float*)d_in[6];
    const float* W2     = (const float*)d_in[7];
    const float* b2     = (const float*)d_in[8];
    const float* Wlin   = (const float*)d_in[9];
    const float* blin   = (const float*)d_in[10];
    float* out = (float*)d_out;

    const int N = in_sizes[0];
    const int E = in_sizes[2];          // edge_type count == E
    const int G = out_size / 2;
    const int TBL = in_sizes[4];        // VOCAB*DD floats

    const int* src = ei;
    const int* dst = ei + E;

    const int K = (N + BKT - 1) / BKT;  // buckets
    const int M = K * 8;                // (bucket, seg) cells
    const int CSRSZ = E + SLACK * K + 64;

    // workspace layout (keep 16-B alignment for csr int4 reads)
    __half* g1h     = (__half*)d_ws;                      // (N+1)*64 halves
    __half* th      = g1h + (size_t)(N + 1) * DD;         // TBL halves
    int*    pairbuf = (int*)(th + TBL);                   // E ints
    int*    csr_src = pairbuf + E;                        // CSRSZ ints
    int*    cursor  = csr_src + CSRSZ;                    // N
    int*    degcnt  = cursor + N;                         // N (padded deg)
    float2* xd      = (float2*)(degcnt + N);              // N+1 float2
    int*    hist    = (int*)(xd + N + 1);                 // M
    float*  outacc  = (float*)(hist + M);                 // 2G  (memset w/ hist)
    int*    cur     = (int*)(outacc + 2 * G);             // M
    int*    bnd     = cur + M;                            // K+1

    const int BT = 256;

    // one memset covers hist + outacc (adjacent)
    hipMemsetAsync(hist, 0, ((size_t)M + 2 * G) * sizeof(int), stream);

    // CSR build: histogram(+table cvt) -> scan -> bucket append -> bucket sort
    bin_count_kernel<<<256, BT, 0, stream>>>(dst, E, hist, K,
                                             (const float2*)table,
                                             (__half2*)th, TBL / 2);
    scan_kernel<<<1, BT, 0, stream>>>(hist, cur, bnd, M, K, E);
    fill_pairs_kernel<<<(E + BT - 1) / BT, BT, 0, stream>>>(src, dst, E, cur, pairbuf);
    build_csr_kernel<<<K, BT, 0, stream>>>(pairbuf, bnd, x, cursor, degcnt, xd,
                                           csr_src, g1h, N);

    // layer 1 (embed+agg+GEMM+relu fused; writes g1h = fp16(dinv*h1))
    int gRow = (N + 15) / 16;
    layer1_kernel<<<gRow, BT, 0, stream>>>(cursor, degcnt, csr_src, xd,
                                           th, W1, b1, g1h, N);
    // layer 2 (agg+GEMM+relu+pool fused)
    layer2_pool_kernel<<<gRow, BT, 0, stream>>>(cursor, degcnt, csr_src, xd,
                                                g1h, W2, b2,
                                                batch, Wlin, outacc, N);
    // final
    final_kernel<<<(G * 2 + BT - 1) / BT, BT, 0, stream>>>(outacc, batch, blin,
                                                           out, G, N);
}

// Round 10
// 336.558 us; speedup vs baseline: 2.7110x; 1.1088x over previous
//
#include <hip/hip_runtime.h>
#include <hip/hip_fp16.h>

// ---------------------------------------------------------------------------
// GCN forward on MI355X — round 10.
//  * MLP via MFMA: per block the GEMM is [16x64]@[64x64]; each wave computes a
//    16x16 tile with 2x mfma_f32_16x16x32_f16.  A = fp16 aggregate in LDS
//    (gather writes fp16 directly, no f32 round-trip); B = W transposed+fp16
//    (WT[n][k], converted in bin_count spare cycles), L1-hot 16B loads.
//    Replaces ~2/3 of the kernels' VALU instructions (round-9 accounting).
//  * Fragment layouts per verified m120/m89: A[m=lane&15][k=quad*8+j],
//    C/D col=lane&15, row=quad*4+reg.
//  * Gather phase unchanged from round 9 (fp16 rows, padded int4 indices).
// ---------------------------------------------------------------------------

#define DD 64          // feature dim
#define DQ 16          // float4s per f32 row (index unit for 8B fp16 chunks)
#define BKT 256        // nodes per bucket
#define MAXK 1024      // max buckets (N <= 262144)
#define SLACK 772      // per-bucket csr slack: 3*256 pad + 4 alignment

typedef _Float16 half8_t __attribute__((ext_vector_type(8)));
typedef float float4_t __attribute__((ext_vector_type(4)));
union F4H8 { float4 f; half8_t h; };
union H2F2 { __half2 h[2]; float2 f; };

static __device__ __forceinline__ void atomAddF(float* p, float v) {
    unsafeAtomicAdd(p, v);   // global_atomic_add_f32 on gfx950
}

// load 4 halves (8B) as two __half2
static __device__ __forceinline__ void h4load(const __half* base, size_t idx8,
                                              __half2& lo, __half2& hi) {
    float2 raw = ((const float2*)base)[idx8];
    lo = *(__half2*)&raw.x;
    hi = *(__half2*)&raw.y;
}

// ---- pass A: bucket histogram (+ fp16 table / W-transpose piggy-backed) ---
__global__ __launch_bounds__(256) void bin_count_kernel(
        const int* __restrict__ dst, int E, int* __restrict__ hist, int K,
        const float2* __restrict__ table2, __half2* __restrict__ th2, int n2,
        const float* __restrict__ W1, const float* __restrict__ W2,
        __half* __restrict__ w1t, __half* __restrict__ w2t) {
    __shared__ int lh[MAXK];
    int tid = threadIdx.x;
    for (int i = tid; i < K; i += 256) lh[i] = 0;
    __syncthreads();
    int stride = gridDim.x * 256;
    for (int i = blockIdx.x * 256 + tid; i < n2; i += stride)
        th2[i] = __float22half2_rn(table2[i]);
    for (int i = blockIdx.x * 256 + tid; i < DD * DD; i += stride) {
        int n = i >> 6, k = i & 63;
        w1t[i] = __float2half(W1[k * DD + n]);   // WT[n][k]
        w2t[i] = __float2half(W2[k * DD + n]);
    }
    for (int e = blockIdx.x * 256 + tid; e < E; e += stride)
        atomicAdd(&lh[((unsigned)dst[e]) >> 8], 1);
    __syncthreads();
    int seg = blockIdx.x & 7;
    for (int b = tid; b < K; b += 256) {
        int c = lh[b];
        if (c) atomicAdd(&hist[b * 8 + seg], c);
    }
}

// ---- pass B: exclusive scan of hist[M] -> cur (append cursors) + bnd ------
__global__ __launch_bounds__(256) void scan_kernel(
        const int* __restrict__ hist, int* __restrict__ cur,
        int* __restrict__ bnd, int M, int K, int E) {
    __shared__ int part[256];
    int tid = threadIdx.x;
    int CH = (M + 255) / 256;
    int base = tid * CH;
    int s = 0;
    for (int i = 0; i < CH; ++i) {
        int idx = base + i;
        if (idx < M) s += hist[idx];
    }
    part[tid] = s;
    __syncthreads();
    if (tid < 64) {
        int carry = 0;
        for (int c = 0; c < 4; ++c) {
            int orig = part[c * 64 + tid];
            int v = orig;
            #pragma unroll
            for (int off = 1; off < 64; off <<= 1) {
                int t = __shfl_up(v, off);
                if (tid >= off) v += t;
            }
            int tot = __shfl(v, 63);
            part[c * 64 + tid] = v - orig + carry;   // exclusive
            carry += tot;
        }
    }
    __syncthreads();
    int run = part[tid];
    for (int i = 0; i < CH; ++i) {
        int idx = base + i;
        if (idx < M) {
            cur[idx] = run;
            if ((idx & 7) == 0) bnd[idx >> 3] = run;
            run += hist[idx];
        }
    }
    if (tid == 0) bnd[K] = E;
}

// ---- pass C: append packed (src | (dst&255)<<24) into bucket segments -----
__global__ __launch_bounds__(256) void fill_pairs_kernel(
        const int* __restrict__ src, const int* __restrict__ dst, int E,
        int* __restrict__ cur, int* __restrict__ pairbuf) {
    int e = blockIdx.x * 256 + threadIdx.x;
    if (e >= E) return;
    int s = src[e], d = dst[e];
    int seg = blockIdx.x & 7;
    int pos = atomicAdd(&cur[(((unsigned)d) >> 8) * 8 + seg], 1);
    pairbuf[pos] = s | ((d & 255) << 24);
}

// ---- pass D: per-bucket padded CSR build + cursor/pdeg/xd (coalesced) -----
__global__ __launch_bounds__(256) void build_csr_kernel(
        const int* __restrict__ pairbuf, const int* __restrict__ bnd,
        const int* __restrict__ x, int* __restrict__ cursor,
        int* __restrict__ degcnt, float2* __restrict__ xd,
        int* __restrict__ csr_src, __half* __restrict__ g1h, int N) {
    __shared__ int cnt[256], basel[256], curl[256];
    int tid = threadIdx.x;
    int b = blockIdx.x;
    int node0 = b << 8;
    cnt[tid] = 0;
    __syncthreads();
    int bb0 = bnd[b], bb1 = bnd[b + 1];
    for (int i = bb0 + tid; i < bb1; i += 256)
        atomicAdd(&cnt[((unsigned)pairbuf[i]) >> 24], 1);
    __syncthreads();
    int c  = cnt[tid];
    int pc = (c + 3) & ~3;              // padded count
    {
        __syncthreads();
        basel[tid] = pc;
        __syncthreads();
        if (tid < 64) {
            int carry = 0;
            for (int cc = 0; cc < 4; ++cc) {
                int orig = basel[cc * 64 + tid];
                int v = orig;
                #pragma unroll
                for (int off = 1; off < 64; off <<= 1) {
                    int t = __shfl_up(v, off);
                    if (tid >= off) v += t;
                }
                int tot = __shfl(v, 63);
                cnt[cc * 64 + tid] = v - orig + carry;   // exclusive
                carry += tot;
            }
        }
        __syncthreads();
    }
    int cb0 = ((bb0 + 3) & ~3) + SLACK * b;   // aligned csr base for bucket
    int node = node0 + tid;
    int myBase = cb0 + cnt[tid];
    curl[tid] = myBase;
    if (node < N) {
        cursor[node] = myBase;
        degcnt[node] = pc;
        xd[node] = make_float2(rsqrtf((float)c + 1.0f), __int_as_float(x[node]));
        for (int t = c; t < pc; ++t) csr_src[myBase + t] = N;   // sentinel pad
    } else if (node == N) {
        xd[N] = make_float2(0.0f, __int_as_float(0));           // zero weight
        float2* z = (float2*)(g1h + (size_t)N * DD);            // zero row N
        for (int t = 0; t < DD / 4; ++t) z[t] = make_float2(0.f, 0.f);
    }
    __syncthreads();
    for (int i = bb0 + tid; i < bb1; i += 256) {
        int pk = pairbuf[i];
        int pos = atomicAdd(&curl[((unsigned)pk) >> 24], 1);
        csr_src[pos] = pk & 0x00FFFFFF;
    }
}

// ---------------- layer 1: agg from fp16 table, MFMA MLP, g1h = f16(dv*h1) --
__global__ __launch_bounds__(256, 8) void layer1_kernel(
        const int* __restrict__ cursor, const int* __restrict__ deg,
        const int* __restrict__ csr_src, const float2* __restrict__ xd,
        const __half* __restrict__ th, const __half* __restrict__ wt,
        const float* __restrict__ bias, __half* __restrict__ g1h, int N) {
    __shared__ float4 Hs4[16 * 8];   // 16 rows x 64 fp16 = 2 KB
    __shared__ float dvs[16];
    int row0 = blockIdx.x * 16;
    int tid = threadIdx.x;
    int node_l = tid >> 4, j = tid & 15;
    int node = row0 + node_l;
    __half2 z = __float2half2_rn(0.f);
    __half2 aL0 = z, aL1 = z, aL2 = z, aL3 = z;
    __half2 aH0 = z, aH1 = z, aH2 = z, aH3 = z;
    float di = 0.f;
    if (node < N) {
        float2 sxd = xd[node];
        di = sxd.x;
        if (j == 0) dvs[node_l] = di;
        __half2 dh = __float2half2_rn(di);
        __half2 lo, hi;
        h4load(th, (size_t)__float_as_int(sxd.y) * DQ + j, lo, hi);
        aL0 = __hmul2(dh, lo);
        aH0 = __hmul2(dh, hi);
        const int4* cs = (const int4*)(csr_src + cursor[node]);  // 16-B aligned
        int nq = deg[node] >> 2;                                 // padded groups
        for (int q = 0; q < nq; ++q) {
            int4 s4 = cs[q];
            float2 pa = xd[s4.x], pb = xd[s4.y], pc_ = xd[s4.z], pd = xd[s4.w];
            __half2 w0 = __float2half2_rn(pa.x);
            __half2 w1 = __float2half2_rn(pb.x);
            __half2 w2 = __float2half2_rn(pc_.x);
            __half2 w3 = __float2half2_rn(pd.x);
            __half2 l0, h0, l1, h1, l2, h2, l3, h3;
            h4load(th, (size_t)__float_as_int(pa.y)  * DQ + j, l0, h0);
            h4load(th, (size_t)__float_as_int(pb.y)  * DQ + j, l1, h1);
            h4load(th, (size_t)__float_as_int(pc_.y) * DQ + j, l2, h2);
            h4load(th, (size_t)__float_as_int(pd.y)  * DQ + j, l3, h3);
            aL0 = __hfma2(w0, l0, aL0); aH0 = __hfma2(w0, h0, aH0);
            aL1 = __hfma2(w1, l1, aL1); aH1 = __hfma2(w1, h1, aH1);
            aL2 = __hfma2(w2, l2, aL2); aH2 = __hfma2(w2, h2, aH2);
            aL3 = __hfma2(w3, l3, aL3); aH3 = __hfma2(w3, h3, aH3);
        }
    }
    aL0 = __hadd2(__hadd2(aL0, aL1), __hadd2(aL2, aL3));
    aH0 = __hadd2(__hadd2(aH0, aH1), __hadd2(aH2, aH3));
    {   // final * di in fp16, store aggregate row to LDS as fp16
        __half2 dih = __float2half2_rn(di);
        H2F2 u;
        u.h[0] = __hmul2(dih, aL0);
        u.h[1] = __hmul2(dih, aH0);
        ((float2*)Hs4)[node_l * 16 + j] = u.f;
    }
    __syncthreads();

    // MFMA MLP: wave computes 16 rows x 16 cols (cols = wave*16..+15), K=64.
    int wave = tid >> 6, lane = tid & 63;
    int m = lane & 15, quad = lane >> 4;
    int ncol = wave * 16 + m;
    F4H8 a0, a1, b0, b1;
    a0.f = Hs4[m * 8 + quad];
    a1.f = Hs4[m * 8 + 4 + quad];
    const float4* WT4 = (const float4*)wt;
    b0.f = WT4[ncol * 8 + quad];
    b1.f = WT4[ncol * 8 + 4 + quad];
    float4_t acc = {0.f, 0.f, 0.f, 0.f};
    acc = __builtin_amdgcn_mfma_f32_16x16x32_f16(a0.h, b0.h, acc, 0, 0, 0);
    acc = __builtin_amdgcn_mfma_f32_16x16x32_f16(a1.h, b1.h, acc, 0, 0, 0);
    float bb = bias[ncol];
    #pragma unroll
    for (int reg = 0; reg < 4; ++reg) {
        int row = quad * 4 + reg;
        int grow = row0 + row;
        if (grow < N) {
            float h = fmaxf(acc[reg] + bb, 0.0f);
            g1h[(size_t)grow * DD + ncol] = __float2half(dvs[row] * h);
        }
    }
}

// -------- layer 2 + pool: gather g1h, MFMA MLP, Wlin dot + segmented pool ---
__global__ __launch_bounds__(256, 8) void layer2_pool_kernel(
        const int* __restrict__ cursor, const int* __restrict__ deg,
        const int* __restrict__ csr_src, const float2* __restrict__ xd,
        const __half* __restrict__ g1h, const __half* __restrict__ wt,
        const float* __restrict__ bias, const int* __restrict__ batch,
        const float* __restrict__ Wlin, float* __restrict__ outacc, int N) {
    __shared__ float4 Hs4[16 * 8];   // 2 KB fp16 aggregate
    __shared__ float lp0[64], lp1[64];   // [wave][row] partial pools
    __shared__ float p0s[16], p1s[16];
    __shared__ int   bat[16];
    int row0 = blockIdx.x * 16;
    int tid = threadIdx.x;
    int node_l = tid >> 4, j = tid & 15;
    int node = row0 + node_l;
    __half2 z = __float2half2_rn(0.f);
    __half2 aL0 = z, aL1 = z, aL2 = z, aL3 = z;
    __half2 aH0 = z, aH1 = z, aH2 = z, aH3 = z;
    float di = 0.f;
    if (node < N) {
        di = xd[node].x;
        h4load(g1h, (size_t)node * DQ + j, aL0, aH0);   // self term, weight 1
        const int4* cs = (const int4*)(csr_src + cursor[node]);
        int nq = deg[node] >> 2;
        for (int q = 0; q < nq; ++q) {
            int4 s4 = cs[q];
            __half2 l0, h0, l1, h1, l2, h2, l3, h3;
            h4load(g1h, (size_t)s4.x * DQ + j, l0, h0);
            h4load(g1h, (size_t)s4.y * DQ + j, l1, h1);
            h4load(g1h, (size_t)s4.z * DQ + j, l2, h2);
            h4load(g1h, (size_t)s4.w * DQ + j, l3, h3);
            aL0 = __hadd2(aL0, l0); aH0 = __hadd2(aH0, h0);
            aL1 = __hadd2(aL1, l1); aH1 = __hadd2(aH1, h1);
            aL2 = __hadd2(aL2, l2); aH2 = __hadd2(aH2, h2);
            aL3 = __hadd2(aL3, l3); aH3 = __hadd2(aH3, h3);
        }
    }
    aL0 = __hadd2(__hadd2(aL0, aL1), __hadd2(aL2, aL3));
    aH0 = __hadd2(__hadd2(aH0, aH1), __hadd2(aH2, aH3));
    {
        __half2 dih = __float2half2_rn(di);
        H2F2 u;
        u.h[0] = __hmul2(dih, aL0);
        u.h[1] = __hmul2(dih, aH0);
        ((float2*)Hs4)[node_l * 16 + j] = u.f;
    }
    __syncthreads();

    int wave = tid >> 6, lane = tid & 63;
    int m = lane & 15, quad = lane >> 4;
    int ncol = wave * 16 + m;
    F4H8 a0, a1, b0, b1;
    a0.f = Hs4[m * 8 + quad];
    a1.f = Hs4[m * 8 + 4 + quad];
    const float4* WT4 = (const float4*)wt;
    b0.f = WT4[ncol * 8 + quad];
    b1.f = WT4[ncol * 8 + 4 + quad];
    float4_t acc = {0.f, 0.f, 0.f, 0.f};
    acc = __builtin_amdgcn_mfma_f32_16x16x32_f16(a0.h, b0.h, acc, 0, 0, 0);
    acc = __builtin_amdgcn_mfma_f32_16x16x32_f16(a1.h, b1.h, acc, 0, 0, 0);
    float bb  = bias[ncol];
    float wl0 = Wlin[ncol * 2 + 0];
    float wl1 = Wlin[ncol * 2 + 1];
    #pragma unroll
    for (int reg = 0; reg < 4; ++reg) {
        int row = quad * 4 + reg;
        int grow = row0 + row;
        float h = (grow < N) ? fmaxf(acc[reg] + bb, 0.0f) : 0.0f;
        float p0 = h * wl0;
        float p1 = h * wl1;
        #pragma unroll
        for (int off = 8; off >= 1; off >>= 1) {   // reduce 16-lane col group
            p0 += __shfl_xor(p0, off);
            p1 += __shfl_xor(p1, off);
        }
        if (m == 0) {
            lp0[wave * 16 + row] = p0;
            lp1[wave * 16 + row] = p1;
        }
    }
    __syncthreads();
    if (tid < 16) {
        int row = tid;
        int grow = row0 + row;
        p0s[row] = lp0[row] + lp0[16 + row] + lp0[32 + row] + lp0[48 + row];
        p1s[row] = lp1[row] + lp1[16 + row] + lp1[32 + row] + lp1[48 + row];
        bat[row] = (grow < N) ? batch[grow] : -1;
    }
    __syncthreads();
    if (tid < 16) {
        int bg = bat[tid];
        bool head = (bg >= 0) && (tid == 0 || bat[tid - 1] != bg);
        if (head) {
            float s0 = 0.f, s1 = 0.f;
            for (int k = tid; k < 16 && bat[k] == bg; ++k) {
                s0 += p0s[k];
                s1 += p1s[k];
            }
            atomAddF(&outacc[bg * 2 + 0], s0);
            atomAddF(&outacc[bg * 2 + 1], s1);
        }
    }
}

// counts via binary search on sorted batch; then divide + blin
__global__ void final_kernel(const float* __restrict__ outacc,
                             const int* __restrict__ batch,
                             const float* __restrict__ blin,
                             float* __restrict__ out, int G, int N) {
    int t = blockIdx.x * blockDim.x + threadIdx.x;
    if (t >= G * 2) return;
    int g = t >> 1, c = t & 1;
    int lo = 0, hi = N;
    while (lo < hi) { int m = (lo + hi) >> 1; if (batch[m] < g) lo = m + 1; else hi = m; }
    int lo2 = lo, hi2 = N;
    while (lo2 < hi2) { int m = (lo2 + hi2) >> 1; if (batch[m] < g + 1) lo2 = m + 1; else hi2 = m; }
    float cnt = (float)(lo2 - lo);
    out[t] = outacc[t] / fmaxf(cnt, 1.0f) + blin[c];
}

extern "C" void kernel_launch(void* const* d_in, const int* in_sizes, int n_in,
                              void* d_out, int out_size, void* d_ws, size_t ws_size,
                              hipStream_t stream) {
    const int*   x      = (const int*)d_in[0];
    const int*   ei     = (const int*)d_in[1];   // [2,E] row-major
    const int*   batch  = (const int*)d_in[3];
    const float* table  = (const float*)d_in[4];
    const float* W1     = (const float*)d_in[5];
    const float* b1     = (const float*)d_in[6];
    const float* W2     = (const float*)d_in[7];
    const float* b2     = (const float*)d_in[8];
    const float* Wlin   = (const float*)d_in[9];
    const float* blin   = (const float*)d_in[10];
    float* out = (float*)d_out;

    const int N = in_sizes[0];
    const int E = in_sizes[2];          // edge_type count == E
    const int G = out_size / 2;
    const int TBL = in_sizes[4];        // VOCAB*DD floats

    const int* src = ei;
    const int* dst = ei + E;

    const int K = (N + BKT - 1) / BKT;  // buckets
    const int M = K * 8;                // (bucket, seg) cells
    const int CSRSZ = E + SLACK * K + 64;

    // workspace layout (keep 16-B alignment for csr int4 reads)
    __half* g1h     = (__half*)d_ws;                      // (N+1)*64 halves
    __half* th      = g1h + (size_t)(N + 1) * DD;         // TBL halves
    __half* w1t     = th + TBL;                           // 4096 halves
    __half* w2t     = w1t + DD * DD;                      // 4096 halves
    int*    pairbuf = (int*)(w2t + DD * DD);              // E ints
    int*    csr_src = pairbuf + E;                        // CSRSZ ints
    int*    cursor  = csr_src + CSRSZ;                    // N
    int*    degcnt  = cursor + N;                         // N (padded deg)
    float2* xd      = (float2*)(degcnt + N);              // N+1 float2
    int*    hist    = (int*)(xd + N + 1);                 // M
    float*  outacc  = (float*)(hist + M);                 // 2G  (memset w/ hist)
    int*    cur     = (int*)(outacc + 2 * G);             // M
    int*    bnd     = cur + M;                            // K+1

    const int BT = 256;

    // one memset covers hist + outacc (adjacent)
    hipMemsetAsync(hist, 0, ((size_t)M + 2 * G) * sizeof(int), stream);

    // CSR build: histogram(+cvt) -> scan -> bucket append -> bucket sort
    bin_count_kernel<<<256, BT, 0, stream>>>(dst, E, hist, K,
                                             (const float2*)table,
                                             (__half2*)th, TBL / 2,
                                             W1, W2, w1t, w2t);
    scan_kernel<<<1, BT, 0, stream>>>(hist, cur, bnd, M, K, E);
    fill_pairs_kernel<<<(E + BT - 1) / BT, BT, 0, stream>>>(src, dst, E, cur, pairbuf);
    build_csr_kernel<<<K, BT, 0, stream>>>(pairbuf, bnd, x, cursor, degcnt, xd,
                                           csr_src, g1h, N);

    // layer 1 (embed+agg+MFMA-MLP+relu fused; writes g1h = fp16(dinv*h1))
    int gRow = (N + 15) / 16;
    layer1_kernel<<<gRow, BT, 0, stream>>>(cursor, degcnt, csr_src, xd,
                                           th, w1t, b1, g1h, N);
    // layer 2 (agg+MFMA-MLP+relu+pool fused)
    layer2_pool_kernel<<<gRow, BT, 0, stream>>>(cursor, degcnt, csr_src, xd,
                                                g1h, w2t, b2,
                                                batch, Wlin, outacc, N);
    // final
    final_kernel<<<(G * 2 + BT - 1) / BT, BT, 0, stream>>>(outacc, batch, blin,
                                                           out, G, N);
}

// Round 11
// 280.121 us; speedup vs baseline: 3.2573x; 1.2015x over previous
//
#include <hip/hip_runtime.h>
#include <hip/hip_fp16.h>

// ---------------------------------------------------------------------------
// GCN forward on MI355X — round 11.
//  * Partition pass rebuilt with block-private cells: cell=(bucket,block),
//    LDS cursors + LDS atomics in fill (round-10 fill_pairs: 59 MB HBM write
//    for 6.4 MB payload + cross-XCD atomic latency -> 80 us).
//    bin_count writes its private histogram row coalesced; scanA scans bucket
//    totals; scanB scans per-bucket across blocks.
//  * Everything else as round 10 (fp16 gather rows, MFMA MLP, fused pool).
// ---------------------------------------------------------------------------

#define DD 64          // feature dim
#define DQ 16          // 8B-chunk index unit per row
#define BKT 256        // nodes per bucket
#define MAXK 1024      // max buckets; also hist/cur row stride
#define NBLK 256       // partition blocks (chunks)
#define SLACK 772      // per-bucket csr slack: 3*256 pad + 4 alignment

typedef _Float16 half8_t __attribute__((ext_vector_type(8)));
typedef float float4_t __attribute__((ext_vector_type(4)));
union F4H8 { float4 f; half8_t h; };
union H2F2 { __half2 h[2]; float2 f; };

static __device__ __forceinline__ void atomAddF(float* p, float v) {
    unsafeAtomicAdd(p, v);   // global_atomic_add_f32 on gfx950
}

// load 4 halves (8B) as two __half2
static __device__ __forceinline__ void h4load(const __half* base, size_t idx8,
                                              __half2& lo, __half2& hi) {
    float2 raw = ((const float2*)base)[idx8];
    lo = *(__half2*)&raw.x;
    hi = *(__half2*)&raw.y;
}

// ---- pass A: per-chunk histogram + bucket totals (+ fp16 conversions) -----
__global__ __launch_bounds__(256) void bin_count_kernel(
        const int* __restrict__ dst, int E, int CH,
        int* __restrict__ hist, int* __restrict__ bt, int K,
        const float2* __restrict__ table2, __half2* __restrict__ th2, int n2,
        const float* __restrict__ W1, const float* __restrict__ W2,
        __half* __restrict__ w1t, __half* __restrict__ w2t) {
    __shared__ int lh[MAXK];
    int tid = threadIdx.x;
    for (int i = tid; i < K; i += 256) lh[i] = 0;
    __syncthreads();
    int stride = gridDim.x * 256;
    for (int i = blockIdx.x * 256 + tid; i < n2; i += stride)
        th2[i] = __float22half2_rn(table2[i]);
    for (int i = blockIdx.x * 256 + tid; i < DD * DD; i += stride) {
        int n = i >> 6, k = i & 63;
        w1t[i] = __float2half(W1[k * DD + n]);   // WT[n][k]
        w2t[i] = __float2half(W2[k * DD + n]);
    }
    int e0 = blockIdx.x * CH;
    int e1 = min(E, e0 + CH);
    for (int e = e0 + tid; e < e1; e += 256)
        atomicAdd(&lh[((unsigned)dst[e]) >> 8], 1);
    __syncthreads();
    for (int b = tid; b < K; b += 256) {
        int c = lh[b];
        hist[blockIdx.x * MAXK + b] = c;     // coalesced private row
        if (c) atomicAdd(&bt[b], c);
    }
}

// ---- pass B1: exclusive scan of bucket totals bt[K] -> bb[K], bb[K]=E -----
__global__ __launch_bounds__(256) void scanA_kernel(
        const int* __restrict__ bt, int* __restrict__ bb, int K, int E) {
    __shared__ int part[256];
    int tid = threadIdx.x;
    int CH2 = (K + 255) / 256;
    int base = tid * CH2;
    int s = 0;
    for (int i = 0; i < CH2; ++i) {
        int idx = base + i;
        if (idx < K) s += bt[idx];
    }
    part[tid] = s;
    __syncthreads();
    if (tid < 64) {
        int carry = 0;
        for (int c = 0; c < 4; ++c) {
            int orig = part[c * 64 + tid];
            int v = orig;
            #pragma unroll
            for (int off = 1; off < 64; off <<= 1) {
                int t = __shfl_up(v, off);
                if (tid >= off) v += t;
            }
            int tot = __shfl(v, 63);
            part[c * 64 + tid] = v - orig + carry;   // exclusive
            carry += tot;
        }
    }
    __syncthreads();
    int run = part[tid];
    for (int i = 0; i < CH2; ++i) {
        int idx = base + i;
        if (idx < K) {
            bb[idx] = run;
            run += bt[idx];
        }
    }
    if (tid == 0) bb[K] = E;
}

// ---- pass B2: per-bucket scan across blocks -> cur[blk][bucket] -----------
__global__ __launch_bounds__(256) void scanB_kernel(
        const int* __restrict__ hist, const int* __restrict__ bb,
        int* __restrict__ cur, int K) {
    int b = blockIdx.x * 256 + threadIdx.x;
    if (b >= K) return;
    int run = bb[b];
    for (int blk = 0; blk < NBLK; ++blk) {
        cur[blk * MAXK + b] = run;
        run += hist[blk * MAXK + b];
    }
}

// ---- pass C: append packed pairs; cursors in LDS (block-private cells) ----
__global__ __launch_bounds__(256) void fill_kernel(
        const int* __restrict__ src, const int* __restrict__ dst, int E, int CH,
        const int* __restrict__ cur, int* __restrict__ pairbuf, int K) {
    __shared__ int lcur[MAXK];
    int tid = threadIdx.x;
    for (int b = tid; b < K; b += 256)
        lcur[b] = cur[blockIdx.x * MAXK + b];
    __syncthreads();
    int e0 = blockIdx.x * CH;
    int e1 = min(E, e0 + CH);
    for (int e = e0 + tid; e < e1; e += 256) {
        int s = src[e], d = dst[e];
        int pos = atomicAdd(&lcur[((unsigned)d) >> 8], 1);
        pairbuf[pos] = s | ((d & 255) << 24);
    }
}

// ---- pass D: per-bucket padded CSR build + cursor/pdeg/xd (coalesced) -----
__global__ __launch_bounds__(256) void build_csr_kernel(
        const int* __restrict__ pairbuf, const int* __restrict__ bnd,
        const int* __restrict__ x, int* __restrict__ cursor,
        int* __restrict__ degcnt, float2* __restrict__ xd,
        int* __restrict__ csr_src, __half* __restrict__ g1h, int N) {
    __shared__ int cnt[256], basel[256], curl[256];
    int tid = threadIdx.x;
    int b = blockIdx.x;
    int node0 = b << 8;
    cnt[tid] = 0;
    __syncthreads();
    int bb0 = bnd[b], bb1 = bnd[b + 1];
    for (int i = bb0 + tid; i < bb1; i += 256)
        atomicAdd(&cnt[((unsigned)pairbuf[i]) >> 24], 1);
    __syncthreads();
    int c  = cnt[tid];
    int pc = (c + 3) & ~3;              // padded count
    {
        __syncthreads();
        basel[tid] = pc;
        __syncthreads();
        if (tid < 64) {
            int carry = 0;
            for (int cc = 0; cc < 4; ++cc) {
                int orig = basel[cc * 64 + tid];
                int v = orig;
                #pragma unroll
                for (int off = 1; off < 64; off <<= 1) {
                    int t = __shfl_up(v, off);
                    if (tid >= off) v += t;
                }
                int tot = __shfl(v, 63);
                cnt[cc * 64 + tid] = v - orig + carry;   // exclusive
                carry += tot;
            }
        }
        __syncthreads();
    }
    int cb0 = ((bb0 + 3) & ~3) + SLACK * b;   // aligned csr base for bucket
    int node = node0 + tid;
    int myBase = cb0 + cnt[tid];
    curl[tid] = myBase;
    if (node < N) {
        cursor[node] = myBase;
        degcnt[node] = pc;
        xd[node] = make_float2(rsqrtf((float)c + 1.0f), __int_as_float(x[node]));
        for (int t = c; t < pc; ++t) csr_src[myBase + t] = N;   // sentinel pad
    } else if (node == N) {
        xd[N] = make_float2(0.0f, __int_as_float(0));           // zero weight
        float2* z = (float2*)(g1h + (size_t)N * DD);            // zero row N
        for (int t = 0; t < DD / 4; ++t) z[t] = make_float2(0.f, 0.f);
    }
    __syncthreads();
    for (int i = bb0 + tid; i < bb1; i += 256) {
        int pk = pairbuf[i];
        int pos = atomicAdd(&curl[((unsigned)pk) >> 24], 1);
        csr_src[pos] = pk & 0x00FFFFFF;
    }
}

// ---------------- layer 1: agg from fp16 table, MFMA MLP, g1h = f16(dv*h1) --
__global__ __launch_bounds__(256, 8) void layer1_kernel(
        const int* __restrict__ cursor, const int* __restrict__ deg,
        const int* __restrict__ csr_src, const float2* __restrict__ xd,
        const __half* __restrict__ th, const __half* __restrict__ wt,
        const float* __restrict__ bias, __half* __restrict__ g1h, int N) {
    __shared__ float4 Hs4[16 * 8];   // 16 rows x 64 fp16 = 2 KB
    __shared__ float dvs[16];
    int row0 = blockIdx.x * 16;
    int tid = threadIdx.x;
    int node_l = tid >> 4, j = tid & 15;
    int node = row0 + node_l;
    __half2 z = __float2half2_rn(0.f);
    __half2 aL0 = z, aL1 = z, aL2 = z, aL3 = z;
    __half2 aH0 = z, aH1 = z, aH2 = z, aH3 = z;
    float di = 0.f;
    if (node < N) {
        float2 sxd = xd[node];
        di = sxd.x;
        if (j == 0) dvs[node_l] = di;
        __half2 dh = __float2half2_rn(di);
        __half2 lo, hi;
        h4load(th, (size_t)__float_as_int(sxd.y) * DQ + j, lo, hi);
        aL0 = __hmul2(dh, lo);
        aH0 = __hmul2(dh, hi);
        const int4* cs = (const int4*)(csr_src + cursor[node]);  // 16-B aligned
        int nq = deg[node] >> 2;                                 // padded groups
        for (int q = 0; q < nq; ++q) {
            int4 s4 = cs[q];
            float2 pa = xd[s4.x], pb = xd[s4.y], pc_ = xd[s4.z], pd = xd[s4.w];
            __half2 w0 = __float2half2_rn(pa.x);
            __half2 w1 = __float2half2_rn(pb.x);
            __half2 w2 = __float2half2_rn(pc_.x);
            __half2 w3 = __float2half2_rn(pd.x);
            __half2 l0, h0, l1, h1, l2, h2, l3, h3;
            h4load(th, (size_t)__float_as_int(pa.y)  * DQ + j, l0, h0);
            h4load(th, (size_t)__float_as_int(pb.y)  * DQ + j, l1, h1);
            h4load(th, (size_t)__float_as_int(pc_.y) * DQ + j, l2, h2);
            h4load(th, (size_t)__float_as_int(pd.y)  * DQ + j, l3, h3);
            aL0 = __hfma2(w0, l0, aL0); aH0 = __hfma2(w0, h0, aH0);
            aL1 = __hfma2(w1, l1, aL1); aH1 = __hfma2(w1, h1, aH1);
            aL2 = __hfma2(w2, l2, aL2); aH2 = __hfma2(w2, h2, aH2);
            aL3 = __hfma2(w3, l3, aL3); aH3 = __hfma2(w3, h3, aH3);
        }
    }
    aL0 = __hadd2(__hadd2(aL0, aL1), __hadd2(aL2, aL3));
    aH0 = __hadd2(__hadd2(aH0, aH1), __hadd2(aH2, aH3));
    {   // final * di in fp16, store aggregate row to LDS as fp16
        __half2 dih = __float2half2_rn(di);
        H2F2 u;
        u.h[0] = __hmul2(dih, aL0);
        u.h[1] = __hmul2(dih, aH0);
        ((float2*)Hs4)[node_l * 16 + j] = u.f;
    }
    __syncthreads();

    // MFMA MLP: wave computes 16 rows x 16 cols (cols = wave*16..+15), K=64.
    int wave = tid >> 6, lane = tid & 63;
    int m = lane & 15, quad = lane >> 4;
    int ncol = wave * 16 + m;
    F4H8 a0, a1, b0, b1;
    a0.f = Hs4[m * 8 + quad];
    a1.f = Hs4[m * 8 + 4 + quad];
    const float4* WT4 = (const float4*)wt;
    b0.f = WT4[ncol * 8 + quad];
    b1.f = WT4[ncol * 8 + 4 + quad];
    float4_t acc = {0.f, 0.f, 0.f, 0.f};
    acc = __builtin_amdgcn_mfma_f32_16x16x32_f16(a0.h, b0.h, acc, 0, 0, 0);
    acc = __builtin_amdgcn_mfma_f32_16x16x32_f16(a1.h, b1.h, acc, 0, 0, 0);
    float bb = bias[ncol];
    #pragma unroll
    for (int reg = 0; reg < 4; ++reg) {
        int row = quad * 4 + reg;
        int grow = row0 + row;
        if (grow < N) {
            float h = fmaxf(acc[reg] + bb, 0.0f);
            g1h[(size_t)grow * DD + ncol] = __float2half(dvs[row] * h);
        }
    }
}

// -------- layer 2 + pool: gather g1h, MFMA MLP, Wlin dot + segmented pool ---
__global__ __launch_bounds__(256, 8) void layer2_pool_kernel(
        const int* __restrict__ cursor, const int* __restrict__ deg,
        const int* __restrict__ csr_src, const float2* __restrict__ xd,
        const __half* __restrict__ g1h, const __half* __restrict__ wt,
        const float* __restrict__ bias, const int* __restrict__ batch,
        const float* __restrict__ Wlin, float* __restrict__ outacc, int N) {
    __shared__ float4 Hs4[16 * 8];   // 2 KB fp16 aggregate
    __shared__ float lp0[64], lp1[64];   // [wave][row] partial pools
    __shared__ float p0s[16], p1s[16];
    __shared__ int   bat[16];
    int row0 = blockIdx.x * 16;
    int tid = threadIdx.x;
    int node_l = tid >> 4, j = tid & 15;
    int node = row0 + node_l;
    __half2 z = __float2half2_rn(0.f);
    __half2 aL0 = z, aL1 = z, aL2 = z, aL3 = z;
    __half2 aH0 = z, aH1 = z, aH2 = z, aH3 = z;
    float di = 0.f;
    if (node < N) {
        di = xd[node].x;
        h4load(g1h, (size_t)node * DQ + j, aL0, aH0);   // self term, weight 1
        const int4* cs = (const int4*)(csr_src + cursor[node]);
        int nq = deg[node] >> 2;
        for (int q = 0; q < nq; ++q) {
            int4 s4 = cs[q];
            __half2 l0, h0, l1, h1, l2, h2, l3, h3;
            h4load(g1h, (size_t)s4.x * DQ + j, l0, h0);
            h4load(g1h, (size_t)s4.y * DQ + j, l1, h1);
            h4load(g1h, (size_t)s4.z * DQ + j, l2, h2);
            h4load(g1h, (size_t)s4.w * DQ + j, l3, h3);
            aL0 = __hadd2(aL0, l0); aH0 = __hadd2(aH0, h0);
            aL1 = __hadd2(aL1, l1); aH1 = __hadd2(aH1, h1);
            aL2 = __hadd2(aL2, l2); aH2 = __hadd2(aH2, h2);
            aL3 = __hadd2(aL3, l3); aH3 = __hadd2(aH3, h3);
        }
    }
    aL0 = __hadd2(__hadd2(aL0, aL1), __hadd2(aL2, aL3));
    aH0 = __hadd2(__hadd2(aH0, aH1), __hadd2(aH2, aH3));
    {
        __half2 dih = __float2half2_rn(di);
        H2F2 u;
        u.h[0] = __hmul2(dih, aL0);
        u.h[1] = __hmul2(dih, aH0);
        ((float2*)Hs4)[node_l * 16 + j] = u.f;
    }
    __syncthreads();

    int wave = tid >> 6, lane = tid & 63;
    int m = lane & 15, quad = lane >> 4;
    int ncol = wave * 16 + m;
    F4H8 a0, a1, b0, b1;
    a0.f = Hs4[m * 8 + quad];
    a1.f = Hs4[m * 8 + 4 + quad];
    const float4* WT4 = (const float4*)wt;
    b0.f = WT4[ncol * 8 + quad];
    b1.f = WT4[ncol * 8 + 4 + quad];
    float4_t acc = {0.f, 0.f, 0.f, 0.f};
    acc = __builtin_amdgcn_mfma_f32_16x16x32_f16(a0.h, b0.h, acc, 0, 0, 0);
    acc = __builtin_amdgcn_mfma_f32_16x16x32_f16(a1.h, b1.h, acc, 0, 0, 0);
    float bb  = bias[ncol];
    float wl0 = Wlin[ncol * 2 + 0];
    float wl1 = Wlin[ncol * 2 + 1];
    #pragma unroll
    for (int reg = 0; reg < 4; ++reg) {
        int row = quad * 4 + reg;
        int grow = row0 + row;
        float h = (grow < N) ? fmaxf(acc[reg] + bb, 0.0f) : 0.0f;
        float p0 = h * wl0;
        float p1 = h * wl1;
        #pragma unroll
        for (int off = 8; off >= 1; off >>= 1) {   // reduce 16-lane col group
            p0 += __shfl_xor(p0, off);
            p1 += __shfl_xor(p1, off);
        }
        if (m == 0) {
            lp0[wave * 16 + row] = p0;
            lp1[wave * 16 + row] = p1;
        }
    }
    __syncthreads();
    if (tid < 16) {
        int row = tid;
        int grow = row0 + row;
        p0s[row] = lp0[row] + lp0[16 + row] + lp0[32 + row] + lp0[48 + row];
        p1s[row] = lp1[row] + lp1[16 + row] + lp1[32 + row] + lp1[48 + row];
        bat[row] = (grow < N) ? batch[grow] : -1;
    }
    __syncthreads();
    if (tid < 16) {
        int bg = bat[tid];
        bool head = (bg >= 0) && (tid == 0 || bat[tid - 1] != bg);
        if (head) {
            float s0 = 0.f, s1 = 0.f;
            for (int k = tid; k < 16 && bat[k] == bg; ++k) {
                s0 += p0s[k];
                s1 += p1s[k];
            }
            atomAddF(&outacc[bg * 2 + 0], s0);
            atomAddF(&outacc[bg * 2 + 1], s1);
        }
    }
}

// counts via binary search on sorted batch; then divide + blin
__global__ void final_kernel(const float* __restrict__ outacc,
                             const int* __restrict__ batch,
                             const float* __restrict__ blin,
                             float* __restrict__ out, int G, int N) {
    int t = blockIdx.x * blockDim.x + threadIdx.x;
    if (t >= G * 2) return;
    int g = t >> 1, c = t & 1;
    int lo = 0, hi = N;
    while (lo < hi) { int m = (lo + hi) >> 1; if (batch[m] < g) lo = m + 1; else hi = m; }
    int lo2 = lo, hi2 = N;
    while (lo2 < hi2) { int m = (lo2 + hi2) >> 1; if (batch[m] < g + 1) lo2 = m + 1; else hi2 = m; }
    float cnt = (float)(lo2 - lo);
    out[t] = outacc[t] / fmaxf(cnt, 1.0f) + blin[c];
}

extern "C" void kernel_launch(void* const* d_in, const int* in_sizes, int n_in,
                              void* d_out, int out_size, void* d_ws, size_t ws_size,
                              hipStream_t stream) {
    const int*   x      = (const int*)d_in[0];
    const int*   ei     = (const int*)d_in[1];   // [2,E] row-major
    const int*   batch  = (const int*)d_in[3];
    const float* table  = (const float*)d_in[4];
    const float* W1     = (const float*)d_in[5];
    const float* b1     = (const float*)d_in[6];
    const float* W2     = (const float*)d_in[7];
    const float* b2     = (const float*)d_in[8];
    const float* Wlin   = (const float*)d_in[9];
    const float* blin   = (const float*)d_in[10];
    float* out = (float*)d_out;

    const int N = in_sizes[0];
    const int E = in_sizes[2];          // edge_type count == E
    const int G = out_size / 2;
    const int TBL = in_sizes[4];        // VOCAB*DD floats

    const int* src = ei;
    const int* dst = ei + E;

    const int K = (N + BKT - 1) / BKT;  // buckets
    const int M = NBLK * MAXK;          // (block, bucket) cells
    const int CH = (E + NBLK - 1) / NBLK;
    const int CSRSZ = E + SLACK * K + 64;

    // workspace layout (keep 16-B alignment for csr int4 reads)
    __half* g1h     = (__half*)d_ws;                      // (N+1)*64 halves
    __half* th      = g1h + (size_t)(N + 1) * DD;         // TBL halves
    __half* w1t     = th + TBL;                           // 4096 halves
    __half* w2t     = w1t + DD * DD;                      // 4096 halves
    int*    pairbuf = (int*)(w2t + DD * DD);              // E ints
    int*    csr_src = pairbuf + E;                        // CSRSZ ints
    int*    cursor  = csr_src + CSRSZ;                    // N
    int*    degcnt  = cursor + N;                         // N (padded deg)
    float2* xd      = (float2*)(degcnt + N);              // N+1 float2
    int*    bt      = (int*)(xd + N + 1);                 // K     (memset)
    float*  outacc  = (float*)(bt + K);                   // 2G    (memset)
    int*    bb      = (int*)(outacc + 2 * G);             // K+1
    int*    hist    = bb + K + 1;                         // M (no init needed)
    int*    cur     = hist + M;                           // M

    const int BT = 256;

    // one memset covers bt + outacc (adjacent)
    hipMemsetAsync(bt, 0, ((size_t)K + 2 * G) * sizeof(int), stream);

    // partition: per-chunk histogram -> bucket scan -> per-bucket block scan
    //            -> LDS-cursor append -> per-bucket CSR sort
    bin_count_kernel<<<NBLK, BT, 0, stream>>>(dst, E, CH, hist, bt, K,
                                              (const float2*)table,
                                              (__half2*)th, TBL / 2,
                                              W1, W2, w1t, w2t);
    scanA_kernel<<<1, BT, 0, stream>>>(bt, bb, K, E);
    scanB_kernel<<<(K + BT - 1) / BT, BT, 0, stream>>>(hist, bb, cur, K);
    fill_kernel<<<NBLK, BT, 0, stream>>>(src, dst, E, CH, cur, pairbuf, K);
    build_csr_kernel<<<K, BT, 0, stream>>>(pairbuf, bb, x, cursor, degcnt, xd,
                                           csr_src, g1h, N);

    // layer 1 (embed+agg+MFMA-MLP+relu fused; writes g1h = fp16(dinv*h1))
    int gRow = (N + 15) / 16;
    layer1_kernel<<<gRow, BT, 0, stream>>>(cursor, degcnt, csr_src, xd,
                                           th, w1t, b1, g1h, N);
    // layer 2 (agg+MFMA-MLP+relu+pool fused)
    layer2_pool_kernel<<<gRow, BT, 0, stream>>>(cursor, degcnt, csr_src, xd,
                                                g1h, w2t, b2,
                                                batch, Wlin, outacc, N);
    // final
    final_kernel<<<(G * 2 + BT - 1) / BT, BT, 0, stream>>>(outacc, batch, blin,
                                                           out, G, N);
}

// Round 12
// 265.492 us; speedup vs baseline: 3.4367x; 1.0551x over previous
//
#include <hip/hip_runtime.h>
#include <hip/hip_fp16.h>

// ---------------------------------------------------------------------------
// GCN forward on MI355X — round 12.
//  * Gather at 8 lanes/node with b128 (16B fp16 chunk) loads: one wave covers
//    8 nodes; ~1.7x fewer wave-instructions per edge than 16-lane/8B (r11
//    layer1: VALUBusy 28%, nothing saturated -> issue/divergence-bound).
//  * Block = 32 nodes; MLP = 2 MFMA tiles per wave (4 mfma_16x16x32_f16).
//  * scanA computes bucket totals from hist (no bt atomics) + zeroes outacc:
//    zero hipMemsetAsync dispatches.
// ---------------------------------------------------------------------------

#define DD 64          // feature dim
#define BKT 256        // nodes per bucket (CSR build)
#define MAXK 1024      // max buckets; hist/cur row stride
#define NBLK 256       // partition blocks (chunks)
#define SLACK 772      // per-bucket csr slack: 3*256 pad + 4 alignment

typedef _Float16 half8_t __attribute__((ext_vector_type(8)));
typedef float float4_t __attribute__((ext_vector_type(4)));
union F4H8 { float4 f; half8_t h; };
union H8   { float4 f; __half2 h[4]; };

static __device__ __forceinline__ void atomAddF(float* p, float v) {
    unsafeAtomicAdd(p, v);   // global_atomic_add_f32 on gfx950
}

// ---- pass A: per-chunk histogram (+ fp16 conversions piggy-backed) --------
__global__ __launch_bounds__(256) void bin_count_kernel(
        const int* __restrict__ dst, int E, int CH,
        int* __restrict__ hist, int K,
        const float2* __restrict__ table2, __half2* __restrict__ th2, int n2,
        const float* __restrict__ W1, const float* __restrict__ W2,
        __half* __restrict__ w1t, __half* __restrict__ w2t) {
    __shared__ int lh[MAXK];
    int tid = threadIdx.x;
    for (int i = tid; i < K; i += 256) lh[i] = 0;
    __syncthreads();
    int stride = gridDim.x * 256;
    for (int i = blockIdx.x * 256 + tid; i < n2; i += stride)
        th2[i] = __float22half2_rn(table2[i]);
    for (int i = blockIdx.x * 256 + tid; i < DD * DD; i += stride) {
        int n = i >> 6, k = i & 63;
        w1t[i] = __float2half(W1[k * DD + n]);   // WT[n][k]
        w2t[i] = __float2half(W2[k * DD + n]);
    }
    int e0 = blockIdx.x * CH;
    int e1 = min(E, e0 + CH);
    for (int e = e0 + tid; e < e1; e += 256)
        atomicAdd(&lh[((unsigned)dst[e]) >> 8], 1);
    __syncthreads();
    for (int b = tid; b < K; b += 256)
        hist[blockIdx.x * MAXK + b] = lh[b];     // coalesced private row
}

// ---- pass B1: bucket totals from hist columns; exclusive scan -> bb; ------
// ---- also zeroes outacc (replaces hipMemset)                        -------
__global__ __launch_bounds__(256) void scanA_kernel(
        const int* __restrict__ hist, int* __restrict__ bb,
        float* __restrict__ outacc, int K, int E, int G2) {
    __shared__ int bts[MAXK];
    __shared__ int part[256];
    int tid = threadIdx.x;
    for (int i = tid; i < G2; i += 256) outacc[i] = 0.f;
    for (int b = tid; b < K; b += 256) {
        int s = 0;
        for (int blk = 0; blk < NBLK; ++blk) s += hist[blk * MAXK + b];
        bts[b] = s;
    }
    __syncthreads();
    int CH2 = (K + 255) / 256;
    int base = tid * CH2;
    int s = 0;
    for (int i = 0; i < CH2; ++i) {
        int idx = base + i;
        if (idx < K) s += bts[idx];
    }
    part[tid] = s;
    __syncthreads();
    if (tid < 64) {
        int carry = 0;
        for (int c = 0; c < 4; ++c) {
            int orig = part[c * 64 + tid];
            int v = orig;
            #pragma unroll
            for (int off = 1; off < 64; off <<= 1) {
                int t = __shfl_up(v, off);
                if (tid >= off) v += t;
            }
            int tot = __shfl(v, 63);
            part[c * 64 + tid] = v - orig + carry;   // exclusive
            carry += tot;
        }
    }
    __syncthreads();
    int run = part[tid];
    for (int i = 0; i < CH2; ++i) {
        int idx = base + i;
        if (idx < K) {
            bb[idx] = run;
            run += bts[idx];
        }
    }
    if (tid == 0) bb[K] = E;
}

// ---- pass B2: per-bucket scan across blocks -> cur[blk][bucket] -----------
__global__ __launch_bounds__(256) void scanB_kernel(
        const int* __restrict__ hist, const int* __restrict__ bb,
        int* __restrict__ cur, int K) {
    int b = blockIdx.x * 256 + threadIdx.x;
    if (b >= K) return;
    int run = bb[b];
    for (int blk = 0; blk < NBLK; ++blk) {
        cur[blk * MAXK + b] = run;
        run += hist[blk * MAXK + b];
    }
}

// ---- pass C: append packed pairs; cursors in LDS (block-private cells) ----
__global__ __launch_bounds__(256) void fill_kernel(
        const int* __restrict__ src, const int* __restrict__ dst, int E, int CH,
        const int* __restrict__ cur, int* __restrict__ pairbuf, int K) {
    __shared__ int lcur[MAXK];
    int tid = threadIdx.x;
    for (int b = tid; b < K; b += 256)
        lcur[b] = cur[blockIdx.x * MAXK + b];
    __syncthreads();
    int e0 = blockIdx.x * CH;
    int e1 = min(E, e0 + CH);
    for (int e = e0 + tid; e < e1; e += 256) {
        int s = src[e], d = dst[e];
        int pos = atomicAdd(&lcur[((unsigned)d) >> 8], 1);
        pairbuf[pos] = s | ((d & 255) << 24);
    }
}

// ---- pass D: per-bucket padded CSR build + cursor/pdeg/xd (coalesced) -----
__global__ __launch_bounds__(256) void build_csr_kernel(
        const int* __restrict__ pairbuf, const int* __restrict__ bnd,
        const int* __restrict__ x, int* __restrict__ cursor,
        int* __restrict__ degcnt, float2* __restrict__ xd,
        int* __restrict__ csr_src, __half* __restrict__ g1h, int N) {
    __shared__ int cnt[256], basel[256], curl[256];
    int tid = threadIdx.x;
    int b = blockIdx.x;
    int node0 = b << 8;
    cnt[tid] = 0;
    __syncthreads();
    int bb0 = bnd[b], bb1 = bnd[b + 1];
    for (int i = bb0 + tid; i < bb1; i += 256)
        atomicAdd(&cnt[((unsigned)pairbuf[i]) >> 24], 1);
    __syncthreads();
    int c  = cnt[tid];
    int pc = (c + 3) & ~3;              // padded count
    {
        __syncthreads();
        basel[tid] = pc;
        __syncthreads();
        if (tid < 64) {
            int carry = 0;
            for (int cc = 0; cc < 4; ++cc) {
                int orig = basel[cc * 64 + tid];
                int v = orig;
                #pragma unroll
                for (int off = 1; off < 64; off <<= 1) {
                    int t = __shfl_up(v, off);
                    if (tid >= off) v += t;
                }
                int tot = __shfl(v, 63);
                cnt[cc * 64 + tid] = v - orig + carry;   // exclusive
                carry += tot;
            }
        }
        __syncthreads();
    }
    int cb0 = ((bb0 + 3) & ~3) + SLACK * b;   // aligned csr base for bucket
    int node = node0 + tid;
    int myBase = cb0 + cnt[tid];
    curl[tid] = myBase;
    if (node < N) {
        cursor[node] = myBase;
        degcnt[node] = pc;
        xd[node] = make_float2(rsqrtf((float)c + 1.0f), __int_as_float(x[node]));
        for (int t = c; t < pc; ++t) csr_src[myBase + t] = N;   // sentinel pad
    } else if (node == N) {
        xd[N] = make_float2(0.0f, __int_as_float(0));           // zero weight
        float2* z = (float2*)(g1h + (size_t)N * DD);            // zero row N
        for (int t = 0; t < DD / 4; ++t) z[t] = make_float2(0.f, 0.f);
    }
    __syncthreads();
    for (int i = bb0 + tid; i < bb1; i += 256) {
        int pk = pairbuf[i];
        int pos = atomicAdd(&curl[((unsigned)pk) >> 24], 1);
        csr_src[pos] = pk & 0x00FFFFFF;
    }
}

// ---------------- layer 1: agg from fp16 table, MFMA MLP, g1h = f16(dv*h1) --
// 8 lanes/node, b128 chunks; block = 32 nodes.
__global__ __launch_bounds__(256, 8) void layer1_kernel(
        const int* __restrict__ cursor, const int* __restrict__ deg,
        const int* __restrict__ csr_src, const float2* __restrict__ xd,
        const float4* __restrict__ th4, const __half* __restrict__ wt,
        const float* __restrict__ bias, __half* __restrict__ g1h, int N) {
    __shared__ float4 Hs4[32 * 8];   // 32 rows x 128B fp16 = 4 KB
    __shared__ float dvs[32];
    int row0 = blockIdx.x * 32;
    int tid = threadIdx.x;
    int node_l = tid >> 3, j3 = tid & 7;
    int node = row0 + node_l;
    H8 acc0, acc1;
    acc0.f = make_float4(0.f, 0.f, 0.f, 0.f);
    acc1.f = acc0.f;
    float di = 0.f;
    if (node < N) {
        float2 sxd = xd[node];
        di = sxd.x;
        if (j3 == 0) dvs[node_l] = di;
        __half2 dh = __float2half2_rn(di);
        H8 tv; tv.f = th4[(size_t)__float_as_int(sxd.y) * 8 + j3];
        acc0.h[0] = __hmul2(dh, tv.h[0]); acc0.h[1] = __hmul2(dh, tv.h[1]);
        acc0.h[2] = __hmul2(dh, tv.h[2]); acc0.h[3] = __hmul2(dh, tv.h[3]);
        const int4* cs = (const int4*)(csr_src + cursor[node]);  // 16-B aligned
        int nq = deg[node] >> 2;
        for (int q = 0; q < nq; ++q) {
            int4 s4 = cs[q];
            float2 pa = xd[s4.x], pb = xd[s4.y], pc_ = xd[s4.z], pd = xd[s4.w];
            __half2 w0 = __float2half2_rn(pa.x);
            __half2 w1 = __float2half2_rn(pb.x);
            __half2 w2 = __float2half2_rn(pc_.x);
            __half2 w3 = __float2half2_rn(pd.x);
            H8 u0, u1, u2, u3;
            u0.f = th4[(size_t)__float_as_int(pa.y)  * 8 + j3];
            u1.f = th4[(size_t)__float_as_int(pb.y)  * 8 + j3];
            u2.f = th4[(size_t)__float_as_int(pc_.y) * 8 + j3];
            u3.f = th4[(size_t)__float_as_int(pd.y)  * 8 + j3];
            #pragma unroll
            for (int t = 0; t < 4; ++t) {
                acc0.h[t] = __hfma2(w0, u0.h[t], acc0.h[t]);
                acc1.h[t] = __hfma2(w1, u1.h[t], acc1.h[t]);
                acc0.h[t] = __hfma2(w2, u2.h[t], acc0.h[t]);
                acc1.h[t] = __hfma2(w3, u3.h[t], acc1.h[t]);
            }
        }
        __half2 dih = dh;
        #pragma unroll
        for (int t = 0; t < 4; ++t)
            acc0.h[t] = __hmul2(dih, __hadd2(acc0.h[t], acc1.h[t]));
    }
    Hs4[node_l * 8 + j3] = acc0.f;   // linear b128, conflict-free
    __syncthreads();

    // MFMA MLP: 2 tiles of 16 rows; each wave does cols wave*16..+15, K=64.
    int wave = tid >> 6, lane = tid & 63;
    int m = lane & 15, quad = lane >> 4;
    int ncol = wave * 16 + m;
    F4H8 b0, b1;
    const float4* WT4 = (const float4*)wt;
    b0.f = WT4[ncol * 8 + quad];
    b1.f = WT4[ncol * 8 + 4 + quad];
    float bb_ = bias[ncol];
    #pragma unroll
    for (int t = 0; t < 2; ++t) {
        F4H8 a0, a1;
        a0.f = Hs4[(t * 16 + m) * 8 + quad];
        a1.f = Hs4[(t * 16 + m) * 8 + 4 + quad];
        float4_t acc = {0.f, 0.f, 0.f, 0.f};
        acc = __builtin_amdgcn_mfma_f32_16x16x32_f16(a0.h, b0.h, acc, 0, 0, 0);
        acc = __builtin_amdgcn_mfma_f32_16x16x32_f16(a1.h, b1.h, acc, 0, 0, 0);
        #pragma unroll
        for (int reg = 0; reg < 4; ++reg) {
            int row = t * 16 + quad * 4 + reg;
            int grow = row0 + row;
            if (grow < N) {
                float h = fmaxf(acc[reg] + bb_, 0.0f);
                g1h[(size_t)grow * DD + ncol] = __float2half(dvs[row] * h);
            }
        }
    }
}

// -------- layer 2 + pool: gather g1h, MFMA MLP, Wlin dot + segmented pool ---
__global__ __launch_bounds__(256, 8) void layer2_pool_kernel(
        const int* __restrict__ cursor, const int* __restrict__ deg,
        const int* __restrict__ csr_src, const float2* __restrict__ xd,
        const float4* __restrict__ g1h4, const __half* __restrict__ wt,
        const float* __restrict__ bias, const int* __restrict__ batch,
        const float* __restrict__ Wlin, float* __restrict__ outacc, int N) {
    __shared__ float4 Hs4[32 * 8];       // 4 KB
    __shared__ float lp0[128], lp1[128]; // [wave][row]
    __shared__ float p0s[32], p1s[32];
    __shared__ int   bat[32];
    int row0 = blockIdx.x * 32;
    int tid = threadIdx.x;
    int node_l = tid >> 3, j3 = tid & 7;
    int node = row0 + node_l;
    H8 acc0, acc1;
    acc0.f = make_float4(0.f, 0.f, 0.f, 0.f);
    acc1.f = acc0.f;
    float di = 0.f;
    if (node < N) {
        di = xd[node].x;
        acc0.f = g1h4[(size_t)node * 8 + j3];   // self term, weight 1
        const int4* cs = (const int4*)(csr_src + cursor[node]);
        int nq = deg[node] >> 2;
        for (int q = 0; q < nq; ++q) {
            int4 s4 = cs[q];
            H8 u0, u1, u2, u3;
            u0.f = g1h4[(size_t)s4.x * 8 + j3];
            u1.f = g1h4[(size_t)s4.y * 8 + j3];
            u2.f = g1h4[(size_t)s4.z * 8 + j3];
            u3.f = g1h4[(size_t)s4.w * 8 + j3];
            #pragma unroll
            for (int t = 0; t < 4; ++t) {
                acc0.h[t] = __hadd2(acc0.h[t], u0.h[t]);
                acc1.h[t] = __hadd2(acc1.h[t], u1.h[t]);
                acc0.h[t] = __hadd2(acc0.h[t], u2.h[t]);
                acc1.h[t] = __hadd2(acc1.h[t], u3.h[t]);
            }
        }
        __half2 dih = __float2half2_rn(di);
        #pragma unroll
        for (int t = 0; t < 4; ++t)
            acc0.h[t] = __hmul2(dih, __hadd2(acc0.h[t], acc1.h[t]));
    }
    Hs4[node_l * 8 + j3] = acc0.f;
    __syncthreads();

    int wave = tid >> 6, lane = tid & 63;
    int m = lane & 15, quad = lane >> 4;
    int ncol = wave * 16 + m;
    F4H8 b0, b1;
    const float4* WT4 = (const float4*)wt;
    b0.f = WT4[ncol * 8 + quad];
    b1.f = WT4[ncol * 8 + 4 + quad];
    float bb_  = bias[ncol];
    float wl0 = Wlin[ncol * 2 + 0];
    float wl1 = Wlin[ncol * 2 + 1];
    #pragma unroll
    for (int t = 0; t < 2; ++t) {
        F4H8 a0, a1;
        a0.f = Hs4[(t * 16 + m) * 8 + quad];
        a1.f = Hs4[(t * 16 + m) * 8 + 4 + quad];
        float4_t acc = {0.f, 0.f, 0.f, 0.f};
        acc = __builtin_amdgcn_mfma_f32_16x16x32_f16(a0.h, b0.h, acc, 0, 0, 0);
        acc = __builtin_amdgcn_mfma_f32_16x16x32_f16(a1.h, b1.h, acc, 0, 0, 0);
        #pragma unroll
        for (int reg = 0; reg < 4; ++reg) {
            int row = t * 16 + quad * 4 + reg;
            int grow = row0 + row;
            float h = (grow < N) ? fmaxf(acc[reg] + bb_, 0.0f) : 0.0f;
            float p0 = h * wl0;
            float p1 = h * wl1;
            #pragma unroll
            for (int off = 8; off >= 1; off >>= 1) {   // sum over 16 cols (m)
                p0 += __shfl_xor(p0, off);
                p1 += __shfl_xor(p1, off);
            }
            if (m == 0) {
                lp0[wave * 32 + row] = p0;
                lp1[wave * 32 + row] = p1;
            }
        }
    }
    __syncthreads();
    if (tid < 32) {
        int grow = row0 + tid;
        p0s[tid] = lp0[tid] + lp0[32 + tid] + lp0[64 + tid] + lp0[96 + tid];
        p1s[tid] = lp1[tid] + lp1[32 + tid] + lp1[64 + tid] + lp1[96 + tid];
        bat[tid] = (grow < N) ? batch[grow] : -1;
    }
    __syncthreads();
    if (tid < 32) {
        int bg = bat[tid];
        bool head = (bg >= 0) && (tid == 0 || bat[tid - 1] != bg);
        if (head) {
            float s0 = 0.f, s1 = 0.f;
            for (int k = tid; k < 32 && bat[k] == bg; ++k) {
                s0 += p0s[k];
                s1 += p1s[k];
            }
            atomAddF(&outacc[bg * 2 + 0], s0);
            atomAddF(&outacc[bg * 2 + 1], s1);
        }
    }
}

// counts via binary search on sorted batch; then divide + blin
__global__ void final_kernel(const float* __restrict__ outacc,
                             const int* __restrict__ batch,
                             const float* __restrict__ blin,
                             float* __restrict__ out, int G, int N) {
    int t = blockIdx.x * blockDim.x + threadIdx.x;
    if (t >= G * 2) return;
    int g = t >> 1, c = t & 1;
    int lo = 0, hi = N;
    while (lo < hi) { int m = (lo + hi) >> 1; if (batch[m] < g) lo = m + 1; else hi = m; }
    int lo2 = lo, hi2 = N;
    while (lo2 < hi2) { int m = (lo2 + hi2) >> 1; if (batch[m] < g + 1) lo2 = m + 1; else hi2 = m; }
    float cnt = (float)(lo2 - lo);
    out[t] = outacc[t] / fmaxf(cnt, 1.0f) + blin[c];
}

extern "C" void kernel_launch(void* const* d_in, const int* in_sizes, int n_in,
                              void* d_out, int out_size, void* d_ws, size_t ws_size,
                              hipStream_t stream) {
    const int*   x      = (const int*)d_in[0];
    const int*   ei     = (const int*)d_in[1];   // [2,E] row-major
    const int*   batch  = (const int*)d_in[3];
    const float* table  = (const float*)d_in[4];
    const float* W1     = (const float*)d_in[5];
    const float* b1     = (const float*)d_in[6];
    const float* W2     = (const float*)d_in[7];
    const float* b2     = (const float*)d_in[8];
    const float* Wlin   = (const float*)d_in[9];
    const float* blin   = (const float*)d_in[10];
    float* out = (float*)d_out;

    const int N = in_sizes[0];
    const int E = in_sizes[2];          // edge_type count == E
    const int G = out_size / 2;
    const int TBL = in_sizes[4];        // VOCAB*DD floats

    const int* src = ei;
    const int* dst = ei + E;

    const int K = (N + BKT - 1) / BKT;  // buckets
    const int M = NBLK * MAXK;          // (block, bucket) cells
    const int CH = (E + NBLK - 1) / NBLK;
    const int CSRSZ = E + SLACK * K + 64;

    // workspace layout (keep 16-B alignment for b128 reads)
    __half* g1h     = (__half*)d_ws;                      // (N+1)*64 halves
    __half* th      = g1h + (size_t)(N + 1) * DD;         // TBL halves
    __half* w1t     = th + TBL;                           // 4096 halves
    __half* w2t     = w1t + DD * DD;                      // 4096 halves
    int*    pairbuf = (int*)(w2t + DD * DD);              // E ints
    int*    csr_src = pairbuf + E;                        // CSRSZ ints
    int*    cursor  = csr_src + CSRSZ;                    // N
    int*    degcnt  = cursor + N;                         // N (padded deg)
    float2* xd      = (float2*)(degcnt + N);              // N+1 float2
    float*  outacc  = (float*)(xd + N + 1);               // 2G (zeroed by scanA)
    int*    bb      = (int*)(outacc + 2 * G);             // K+1
    int*    hist    = bb + K + 1;                         // M
    int*    cur     = hist + M;                           // M

    const int BT = 256;

    // partition: per-chunk histogram -> bucket scan (+outacc zero) ->
    //            per-bucket block scan -> LDS-cursor append -> CSR sort
    bin_count_kernel<<<NBLK, BT, 0, stream>>>(dst, E, CH, hist, K,
                                              (const float2*)table,
                                              (__half2*)th, TBL / 2,
                                              W1, W2, w1t, w2t);
    scanA_kernel<<<1, BT, 0, stream>>>(hist, bb, outacc, K, E, 2 * G);
    scanB_kernel<<<(K + BT - 1) / BT, BT, 0, stream>>>(hist, bb, cur, K);
    fill_kernel<<<NBLK, BT, 0, stream>>>(src, dst, E, CH, cur, pairbuf, K);
    build_csr_kernel<<<K, BT, 0, stream>>>(pairbuf, bb, x, cursor, degcnt, xd,
                                           csr_src, g1h, N);

    // layer 1 (embed+agg+MFMA-MLP+relu fused; writes g1h = fp16(dinv*h1))
    int gRow = (N + 31) / 32;
    layer1_kernel<<<gRow, BT, 0, stream>>>(cursor, degcnt, csr_src, xd,
                                           (const float4*)th, w1t, b1, g1h, N);
    // layer 2 (agg+MFMA-MLP+relu+pool fused)
    layer2_pool_kernel<<<gRow, BT, 0, stream>>>(cursor, degcnt, csr_src, xd,
                                                (const float4*)g1h, w2t, b2,
                                                batch, Wlin, outacc, N);
    // final
    final_kernel<<<(G * 2 + BT - 1) / BT, BT, 0, stream>>>(outacc, batch, blin,
                                                           out, G, N);
}

// Round 13
// 240.311 us; speedup vs baseline: 3.7968x; 1.1048x over previous
//
#include <hip/hip_runtime.h>
#include <hip/hip_fp16.h>

// ---------------------------------------------------------------------------
// GCN forward on MI355X — round 13.
//  * scanA split: totals_kernel (parallel coalesced column sums + outacc
//    zeroing, 16 blocks) + scan_bb (1 block over K totals).  Round-12 scanA
//    did 200k strided loads on ONE CU.
//  * Hs LDS row stride padded 8->9 float4s: MFMA A-frag read had 16-way bank
//    conflicts (1.35M SQ_LDS_BANK_CONFLICT); (m+quad)%8 -> free 2-way now.
//  * rowinfo int2 = (csr base, padded deg): one 8-B broadcast per node.
//  * Rest as round 12 (8-lane b128 fp16 gather, 32-node blocks, MFMA MLP).
// ---------------------------------------------------------------------------

#define DD 64          // feature dim
#define BKT 256        // nodes per bucket (CSR build)
#define MAXK 1024      // max buckets; hist/cur row stride
#define NBLK 256       // partition blocks (chunks)
#define SLACK 772      // per-bucket csr slack: 3*256 pad + 4 alignment

typedef _Float16 half8_t __attribute__((ext_vector_type(8)));
typedef float float4_t __attribute__((ext_vector_type(4)));
union F4H8 { float4 f; half8_t h; };
union H8   { float4 f; __half2 h[4]; };

static __device__ __forceinline__ void atomAddF(float* p, float v) {
    unsafeAtomicAdd(p, v);   // global_atomic_add_f32 on gfx950
}

// ---- pass A: per-chunk histogram (+ fp16 conversions piggy-backed) --------
__global__ __launch_bounds__(256) void bin_count_kernel(
        const int* __restrict__ dst, int E, int CH,
        int* __restrict__ hist, int K,
        const float2* __restrict__ table2, __half2* __restrict__ th2, int n2,
        const float* __restrict__ W1, const float* __restrict__ W2,
        __half* __restrict__ w1t, __half* __restrict__ w2t) {
    __shared__ int lh[MAXK];
    int tid = threadIdx.x;
    for (int i = tid; i < K; i += 256) lh[i] = 0;
    __syncthreads();
    int stride = gridDim.x * 256;
    for (int i = blockIdx.x * 256 + tid; i < n2; i += stride)
        th2[i] = __float22half2_rn(table2[i]);
    for (int i = blockIdx.x * 256 + tid; i < DD * DD; i += stride) {
        int n = i >> 6, k = i & 63;
        w1t[i] = __float2half(W1[k * DD + n]);   // WT[n][k]
        w2t[i] = __float2half(W2[k * DD + n]);
    }
    int e0 = blockIdx.x * CH;
    int e1 = min(E, e0 + CH);
    for (int e = e0 + tid; e < e1; e += 256)
        atomicAdd(&lh[((unsigned)dst[e]) >> 8], 1);
    __syncthreads();
    for (int b = tid; b < K; b += 256)
        hist[blockIdx.x * MAXK + b] = lh[b];     // coalesced private row
}

// ---- pass B0: bucket totals (parallel, coalesced) + zero outacc -----------
__global__ __launch_bounds__(256) void totals_kernel(
        const int* __restrict__ hist, int* __restrict__ bts,
        float* __restrict__ outacc, int K, int G2) {
    int g0 = blockIdx.x * 256 + threadIdx.x;
    int stride = gridDim.x * 256;
    for (int i = g0; i < G2; i += stride) outacc[i] = 0.f;
    for (int b = g0; b < K; b += stride) {
        int s = 0;
        for (int blk = 0; blk < NBLK; ++blk) s += hist[blk * MAXK + b];
        bts[b] = s;
    }
}

// ---- pass B1: exclusive scan of bts[K] -> bb; bb[K] = E -------------------
__global__ __launch_bounds__(256) void scan_bb_kernel(
        const int* __restrict__ bts, int* __restrict__ bb, int K, int E) {
    __shared__ int part[256];
    int tid = threadIdx.x;
    int CH2 = (K + 255) / 256;
    int base = tid * CH2;
    int s = 0;
    for (int i = 0; i < CH2; ++i) {
        int idx = base + i;
        if (idx < K) s += bts[idx];
    }
    part[tid] = s;
    __syncthreads();
    if (tid < 64) {
        int carry = 0;
        for (int c = 0; c < 4; ++c) {
            int orig = part[c * 64 + tid];
            int v = orig;
            #pragma unroll
            for (int off = 1; off < 64; off <<= 1) {
                int t = __shfl_up(v, off);
                if (tid >= off) v += t;
            }
            int tot = __shfl(v, 63);
            part[c * 64 + tid] = v - orig + carry;   // exclusive
            carry += tot;
        }
    }
    __syncthreads();
    int run = part[tid];
    for (int i = 0; i < CH2; ++i) {
        int idx = base + i;
        if (idx < K) {
            bb[idx] = run;
            run += bts[idx];
        }
    }
    if (tid == 0) bb[K] = E;
}

// ---- pass B2: per-bucket scan across blocks -> cur[blk][bucket] -----------
__global__ __launch_bounds__(256) void scanB_kernel(
        const int* __restrict__ hist, const int* __restrict__ bb,
        int* __restrict__ cur, int K) {
    int b = blockIdx.x * 256 + threadIdx.x;
    if (b >= K) return;
    int run = bb[b];
    for (int blk = 0; blk < NBLK; ++blk) {
        cur[blk * MAXK + b] = run;
        run += hist[blk * MAXK + b];
    }
}

// ---- pass C: append packed pairs; cursors in LDS (block-private cells) ----
__global__ __launch_bounds__(256) void fill_kernel(
        const int* __restrict__ src, const int* __restrict__ dst, int E, int CH,
        const int* __restrict__ cur, int* __restrict__ pairbuf, int K) {
    __shared__ int lcur[MAXK];
    int tid = threadIdx.x;
    for (int b = tid; b < K; b += 256)
        lcur[b] = cur[blockIdx.x * MAXK + b];
    __syncthreads();
    int e0 = blockIdx.x * CH;
    int e1 = min(E, e0 + CH);
    for (int e = e0 + tid; e < e1; e += 256) {
        int s = src[e], d = dst[e];
        int pos = atomicAdd(&lcur[((unsigned)d) >> 8], 1);
        pairbuf[pos] = s | ((d & 255) << 24);
    }
}

// ---- pass D: per-bucket padded CSR build + rowinfo/xd (coalesced) ---------
__global__ __launch_bounds__(256) void build_csr_kernel(
        const int* __restrict__ pairbuf, const int* __restrict__ bnd,
        const int* __restrict__ x, int2* __restrict__ rowinfo,
        float2* __restrict__ xd,
        int* __restrict__ csr_src, __half* __restrict__ g1h, int N) {
    __shared__ int cnt[256], basel[256], curl[256];
    int tid = threadIdx.x;
    int b = blockIdx.x;
    int node0 = b << 8;
    cnt[tid] = 0;
    __syncthreads();
    int bb0 = bnd[b], bb1 = bnd[b + 1];
    for (int i = bb0 + tid; i < bb1; i += 256)
        atomicAdd(&cnt[((unsigned)pairbuf[i]) >> 24], 1);
    __syncthreads();
    int c  = cnt[tid];
    int pc = (c + 3) & ~3;              // padded count
    {
        __syncthreads();
        basel[tid] = pc;
        __syncthreads();
        if (tid < 64) {
            int carry = 0;
            for (int cc = 0; cc < 4; ++cc) {
                int orig = basel[cc * 64 + tid];
                int v = orig;
                #pragma unroll
                for (int off = 1; off < 64; off <<= 1) {
                    int t = __shfl_up(v, off);
                    if (tid >= off) v += t;
                }
                int tot = __shfl(v, 63);
                cnt[cc * 64 + tid] = v - orig + carry;   // exclusive
                carry += tot;
            }
        }
        __syncthreads();
    }
    int cb0 = ((bb0 + 3) & ~3) + SLACK * b;   // aligned csr base for bucket
    int node = node0 + tid;
    int myBase = cb0 + cnt[tid];
    curl[tid] = myBase;
    if (node < N) {
        rowinfo[node] = make_int2(myBase, pc);
        xd[node] = make_float2(rsqrtf((float)c + 1.0f), __int_as_float(x[node]));
        for (int t = c; t < pc; ++t) csr_src[myBase + t] = N;   // sentinel pad
    } else if (node == N) {
        xd[N] = make_float2(0.0f, __int_as_float(0));           // zero weight
        float2* z = (float2*)(g1h + (size_t)N * DD);            // zero row N
        for (int t = 0; t < DD / 4; ++t) z[t] = make_float2(0.f, 0.f);
    }
    __syncthreads();
    for (int i = bb0 + tid; i < bb1; i += 256) {
        int pk = pairbuf[i];
        int pos = atomicAdd(&curl[((unsigned)pk) >> 24], 1);
        csr_src[pos] = pk & 0x00FFFFFF;
    }
}

// ---------------- layer 1: agg from fp16 table, MFMA MLP, g1h = f16(dv*h1) --
// 8 lanes/node, b128 chunks; block = 32 nodes; Hs stride 9 (bank-conflict pad)
__global__ __launch_bounds__(256, 8) void layer1_kernel(
        const int2* __restrict__ rowinfo,
        const int* __restrict__ csr_src, const float2* __restrict__ xd,
        const float4* __restrict__ th4, const __half* __restrict__ wt,
        const float* __restrict__ bias, __half* __restrict__ g1h, int N) {
    __shared__ float4 Hs4[32 * 9];   // padded stride 9
    __shared__ float dvs[32];
    int row0 = blockIdx.x * 32;
    int tid = threadIdx.x;
    int node_l = tid >> 3, j3 = tid & 7;
    int node = row0 + node_l;
    H8 acc0, acc1;
    acc0.f = make_float4(0.f, 0.f, 0.f, 0.f);
    acc1.f = acc0.f;
    if (node < N) {
        float2 sxd = xd[node];
        float di = sxd.x;
        if (j3 == 0) dvs[node_l] = di;
        __half2 dh = __float2half2_rn(di);
        H8 tv; tv.f = th4[(size_t)__float_as_int(sxd.y) * 8 + j3];
        acc0.h[0] = __hmul2(dh, tv.h[0]); acc0.h[1] = __hmul2(dh, tv.h[1]);
        acc0.h[2] = __hmul2(dh, tv.h[2]); acc0.h[3] = __hmul2(dh, tv.h[3]);
        int2 ri = rowinfo[node];
        const int4* cs = (const int4*)(csr_src + ri.x);
        int nq = ri.y >> 2;
        for (int q = 0; q < nq; ++q) {
            int4 s4 = cs[q];
            float2 pa = xd[s4.x], pb = xd[s4.y], pc_ = xd[s4.z], pd = xd[s4.w];
            __half2 w0 = __float2half2_rn(pa.x);
            __half2 w1 = __float2half2_rn(pb.x);
            __half2 w2 = __float2half2_rn(pc_.x);
            __half2 w3 = __float2half2_rn(pd.x);
            H8 u0, u1, u2, u3;
            u0.f = th4[(size_t)__float_as_int(pa.y)  * 8 + j3];
            u1.f = th4[(size_t)__float_as_int(pb.y)  * 8 + j3];
            u2.f = th4[(size_t)__float_as_int(pc_.y) * 8 + j3];
            u3.f = th4[(size_t)__float_as_int(pd.y)  * 8 + j3];
            #pragma unroll
            for (int t = 0; t < 4; ++t) {
                acc0.h[t] = __hfma2(w0, u0.h[t], acc0.h[t]);
                acc1.h[t] = __hfma2(w1, u1.h[t], acc1.h[t]);
                acc0.h[t] = __hfma2(w2, u2.h[t], acc0.h[t]);
                acc1.h[t] = __hfma2(w3, u3.h[t], acc1.h[t]);
            }
        }
        #pragma unroll
        for (int t = 0; t < 4; ++t)
            acc0.h[t] = __hmul2(dh, __hadd2(acc0.h[t], acc1.h[t]));
    }
    Hs4[node_l * 9 + j3] = acc0.f;
    __syncthreads();

    // MFMA MLP: 2 tiles of 16 rows; each wave does cols wave*16..+15, K=64.
    int wave = tid >> 6, lane = tid & 63;
    int m = lane & 15, quad = lane >> 4;
    int ncol = wave * 16 + m;
    F4H8 b0, b1;
    const float4* WT4 = (const float4*)wt;
    b0.f = WT4[ncol * 8 + quad];
    b1.f = WT4[ncol * 8 + 4 + quad];
    float bb_ = bias[ncol];
    #pragma unroll
    for (int t = 0; t < 2; ++t) {
        F4H8 a0, a1;
        a0.f = Hs4[(t * 16 + m) * 9 + quad];
        a1.f = Hs4[(t * 16 + m) * 9 + 4 + quad];
        float4_t acc = {0.f, 0.f, 0.f, 0.f};
        acc = __builtin_amdgcn_mfma_f32_16x16x32_f16(a0.h, b0.h, acc, 0, 0, 0);
        acc = __builtin_amdgcn_mfma_f32_16x16x32_f16(a1.h, b1.h, acc, 0, 0, 0);
        #pragma unroll
        for (int reg = 0; reg < 4; ++reg) {
            int row = t * 16 + quad * 4 + reg;
            int grow = row0 + row;
            if (grow < N) {
                float h = fmaxf(acc[reg] + bb_, 0.0f);
                g1h[(size_t)grow * DD + ncol] = __float2half(dvs[row] * h);
            }
        }
    }
}

// -------- layer 2 + pool: gather g1h, MFMA MLP, Wlin dot + segmented pool ---
__global__ __launch_bounds__(256, 8) void layer2_pool_kernel(
        const int2* __restrict__ rowinfo,
        const int* __restrict__ csr_src, const float2* __restrict__ xd,
        const float4* __restrict__ g1h4, const __half* __restrict__ wt,
        const float* __restrict__ bias, const int* __restrict__ batch,
        const float* __restrict__ Wlin, float* __restrict__ outacc, int N) {
    __shared__ float4 Hs4[32 * 9];       // padded stride 9
    __shared__ float lp0[128], lp1[128]; // [wave][row]
    __shared__ float p0s[32], p1s[32];
    __shared__ int   bat[32];
    int row0 = blockIdx.x * 32;
    int tid = threadIdx.x;
    int node_l = tid >> 3, j3 = tid & 7;
    int node = row0 + node_l;
    H8 acc0, acc1;
    acc0.f = make_float4(0.f, 0.f, 0.f, 0.f);
    acc1.f = acc0.f;
    if (node < N) {
        float di = xd[node].x;
        acc0.f = g1h4[(size_t)node * 8 + j3];   // self term, weight 1
        int2 ri = rowinfo[node];
        const int4* cs = (const int4*)(csr_src + ri.x);
        int nq = ri.y >> 2;
        for (int q = 0; q < nq; ++q) {
            int4 s4 = cs[q];
            H8 u0, u1, u2, u3;
            u0.f = g1h4[(size_t)s4.x * 8 + j3];
            u1.f = g1h4[(size_t)s4.y * 8 + j3];
            u2.f = g1h4[(size_t)s4.z * 8 + j3];
            u3.f = g1h4[(size_t)s4.w * 8 + j3];
            #pragma unroll
            for (int t = 0; t < 4; ++t) {
                acc0.h[t] = __hadd2(acc0.h[t], u0.h[t]);
                acc1.h[t] = __hadd2(acc1.h[t], u1.h[t]);
                acc0.h[t] = __hadd2(acc0.h[t], u2.h[t]);
                acc1.h[t] = __hadd2(acc1.h[t], u3.h[t]);
            }
        }
        __half2 dih = __float2half2_rn(di);
        #pragma unroll
        for (int t = 0; t < 4; ++t)
            acc0.h[t] = __hmul2(dih, __hadd2(acc0.h[t], acc1.h[t]));
    }
    Hs4[node_l * 9 + j3] = acc0.f;
    __syncthreads();

    int wave = tid >> 6, lane = tid & 63;
    int m = lane & 15, quad = lane >> 4;
    int ncol = wave * 16 + m;
    F4H8 b0, b1;
    const float4* WT4 = (const float4*)wt;
    b0.f = WT4[ncol * 8 + quad];
    b1.f = WT4[ncol * 8 + 4 + quad];
    float bb_  = bias[ncol];
    float wl0 = Wlin[ncol * 2 + 0];
    float wl1 = Wlin[ncol * 2 + 1];
    #pragma unroll
    for (int t = 0; t < 2; ++t) {
        F4H8 a0, a1;
        a0.f = Hs4[(t * 16 + m) * 9 + quad];
        a1.f = Hs4[(t * 16 + m) * 9 + 4 + quad];
        float4_t acc = {0.f, 0.f, 0.f, 0.f};
        acc = __builtin_amdgcn_mfma_f32_16x16x32_f16(a0.h, b0.h, acc, 0, 0, 0);
        acc = __builtin_amdgcn_mfma_f32_16x16x32_f16(a1.h, b1.h, acc, 0, 0, 0);
        #pragma unroll
        for (int reg = 0; reg < 4; ++reg) {
            int row = t * 16 + quad * 4 + reg;
            int grow = row0 + row;
            float h = (grow < N) ? fmaxf(acc[reg] + bb_, 0.0f) : 0.0f;
            float p0 = h * wl0;
            float p1 = h * wl1;
            #pragma unroll
            for (int off = 8; off >= 1; off >>= 1) {   // sum over 16 cols (m)
                p0 += __shfl_xor(p0, off);
                p1 += __shfl_xor(p1, off);
            }
            if (m == 0) {
                lp0[wave * 32 + row] = p0;
                lp1[wave * 32 + row] = p1;
            }
        }
    }
    __syncthreads();
    if (tid < 32) {
        int grow = row0 + tid;
        p0s[tid] = lp0[tid] + lp0[32 + tid] + lp0[64 + tid] + lp0[96 + tid];
        p1s[tid] = lp1[tid] + lp1[32 + tid] + lp1[64 + tid] + lp1[96 + tid];
        bat[tid] = (grow < N) ? batch[grow] : -1;
    }
    __syncthreads();
    if (tid < 32) {
        int bg = bat[tid];
        bool head = (bg >= 0) && (tid == 0 || bat[tid - 1] != bg);
        if (head) {
            float s0 = 0.f, s1 = 0.f;
            for (int k = tid; k < 32 && bat[k] == bg; ++k) {
                s0 += p0s[k];
                s1 += p1s[k];
            }
            atomAddF(&outacc[bg * 2 + 0], s0);
            atomAddF(&outacc[bg * 2 + 1], s1);
        }
    }
}

// counts via binary search on sorted batch; then divide + blin
__global__ void final_kernel(const float* __restrict__ outacc,
                             const int* __restrict__ batch,
                             const float* __restrict__ blin,
                             float* __restrict__ out, int G, int N) {
    int t = blockIdx.x * blockDim.x + threadIdx.x;
    if (t >= G * 2) return;
    int g = t >> 1, c = t & 1;
    int lo = 0, hi = N;
    while (lo < hi) { int m = (lo + hi) >> 1; if (batch[m] < g) lo = m + 1; else hi = m; }
    int lo2 = lo, hi2 = N;
    while (lo2 < hi2) { int m = (lo2 + hi2) >> 1; if (batch[m] < g + 1) lo2 = m + 1; else hi2 = m; }
    float cnt = (float)(lo2 - lo);
    out[t] = outacc[t] / fmaxf(cnt, 1.0f) + blin[c];
}

extern "C" void kernel_launch(void* const* d_in, const int* in_sizes, int n_in,
                              void* d_out, int out_size, void* d_ws, size_t ws_size,
                              hipStream_t stream) {
    const int*   x      = (const int*)d_in[0];
    const int*   ei     = (const int*)d_in[1];   // [2,E] row-major
    const int*   batch  = (const int*)d_in[3];
    const float* table  = (const float*)d_in[4];
    const float* W1     = (const float*)d_in[5];
    const float* b1     = (const float*)d_in[6];
    const float* W2     = (const float*)d_in[7];
    const float* b2     = (const float*)d_in[8];
    const float* Wlin   = (const float*)d_in[9];
    const float* blin   = (const float*)d_in[10];
    float* out = (float*)d_out;

    const int N = in_sizes[0];
    const int E = in_sizes[2];          // edge_type count == E
    const int G = out_size / 2;
    const int TBL = in_sizes[4];        // VOCAB*DD floats

    const int* src = ei;
    const int* dst = ei + E;

    const int K = (N + BKT - 1) / BKT;  // buckets
    const int M = NBLK * MAXK;          // (block, bucket) cells
    const int CH = (E + NBLK - 1) / NBLK;
    const int CSRSZ = E + SLACK * K + 64;

    // workspace layout (keep 16-B alignment for b128 reads)
    __half* g1h     = (__half*)d_ws;                      // (N+1)*64 halves
    __half* th      = g1h + (size_t)(N + 1) * DD;         // TBL halves
    __half* w1t     = th + TBL;                           // 4096 halves
    __half* w2t     = w1t + DD * DD;                      // 4096 halves
    int*    pairbuf = (int*)(w2t + DD * DD);              // E ints
    int*    csr_src = pairbuf + E;                        // CSRSZ ints
    int2*   rowinfo = (int2*)(csr_src + CSRSZ);           // N int2
    float2* xd      = (float2*)(rowinfo + N);             // N+1 float2
    float*  outacc  = (float*)(xd + N + 1);               // 2G (zeroed in totals)
    int*    bb      = (int*)(outacc + 2 * G);             // K+1
    int*    bts     = bb + K + 1;                         // K
    int*    hist    = bts + K;                            // M
    int*    cur     = hist + M;                           // M

    const int BT = 256;

    // partition: per-chunk histogram -> totals(+outacc zero) -> bucket scan
    //            -> per-bucket block scan -> LDS-cursor append -> CSR sort
    bin_count_kernel<<<NBLK, BT, 0, stream>>>(dst, E, CH, hist, K,
                                              (const float2*)table,
                                              (__half2*)th, TBL / 2,
                                              W1, W2, w1t, w2t);
    totals_kernel<<<16, BT, 0, stream>>>(hist, bts, outacc, K, 2 * G);
    scan_bb_kernel<<<1, BT, 0, stream>>>(bts, bb, K, E);
    scanB_kernel<<<(K + BT - 1) / BT, BT, 0, stream>>>(hist, bb, cur, K);
    fill_kernel<<<NBLK, BT, 0, stream>>>(src, dst, E, CH, cur, pairbuf, K);
    build_csr_kernel<<<K, BT, 0, stream>>>(pairbuf, bb, x, rowinfo, xd,
                                           csr_src, g1h, N);

    // layer 1 (embed+agg+MFMA-MLP+relu fused; writes g1h = fp16(dinv*h1))
    int gRow = (N + 31) / 32;
    layer1_kernel<<<gRow, BT, 0, stream>>>(rowinfo, csr_src, xd,
                                           (const float4*)th, w1t, b1, g1h, N);
    // layer 2 (agg+MFMA-MLP+relu+pool fused)
    layer2_pool_kernel<<<gRow, BT, 0, stream>>>(rowinfo, csr_src, xd,
                                                (const float4*)g1h, w2t, b2,
                                                batch, Wlin, outacc, N);
    // final
    final_kernel<<<(G * 2 + BT - 1) / BT, BT, 0, stream>>>(outacc, batch, blin,
                                                           out, G, N);
}

// Round 14
// 240.232 us; speedup vs baseline: 3.7981x; 1.0003x over previous
//
#include <hip/hip_runtime.h>
#include <hip/hip_fp16.h>

// ---------------------------------------------------------------------------
// GCN forward on MI355X — round 14.
//  * Gather loop unrolled x2 (8 edges/iter: 2 idx int4 + 8 row b128 loads in
//    flight): r13 layer2 profile (VALU 30%, HBM 29%, nothing saturated) says
//    latency-bound with too few outstanding lines per wave.
//  * __launch_bounds__(256,6) on layers: ~85 VGPR budget so the 8 loads stay
//    in flight (measured occupancy was ~5 blocks/CU; cap 6 costs nothing).
//  * scanB wave-parallel: one wave per bucket (782 waves vs 782 threads).
//  * Rest as round 13.
// ---------------------------------------------------------------------------

#define DD 64          // feature dim
#define BKT 256        // nodes per bucket (CSR build)
#define MAXK 1024      // max buckets; hist/cur row stride
#define NBLK 256       // partition blocks (chunks)
#define SLACK 772      // per-bucket csr slack: 3*256 pad + 4 alignment

typedef _Float16 half8_t __attribute__((ext_vector_type(8)));
typedef float float4_t __attribute__((ext_vector_type(4)));
union F4H8 { float4 f; half8_t h; };
union H8   { float4 f; __half2 h[4]; };

static __device__ __forceinline__ void atomAddF(float* p, float v) {
    unsafeAtomicAdd(p, v);   // global_atomic_add_f32 on gfx950
}

// ---- pass A: per-chunk histogram (+ fp16 conversions piggy-backed) --------
__global__ __launch_bounds__(256) void bin_count_kernel(
        const int* __restrict__ dst, int E, int CH,
        int* __restrict__ hist, int K,
        const float2* __restrict__ table2, __half2* __restrict__ th2, int n2,
        const float* __restrict__ W1, const float* __restrict__ W2,
        __half* __restrict__ w1t, __half* __restrict__ w2t) {
    __shared__ int lh[MAXK];
    int tid = threadIdx.x;
    for (int i = tid; i < K; i += 256) lh[i] = 0;
    __syncthreads();
    int stride = gridDim.x * 256;
    for (int i = blockIdx.x * 256 + tid; i < n2; i += stride)
        th2[i] = __float22half2_rn(table2[i]);
    for (int i = blockIdx.x * 256 + tid; i < DD * DD; i += stride) {
        int n = i >> 6, k = i & 63;
        w1t[i] = __float2half(W1[k * DD + n]);   // WT[n][k]
        w2t[i] = __float2half(W2[k * DD + n]);
    }
    int e0 = blockIdx.x * CH;
    int e1 = min(E, e0 + CH);
    for (int e = e0 + tid; e < e1; e += 256)
        atomicAdd(&lh[((unsigned)dst[e]) >> 8], 1);
    __syncthreads();
    for (int b = tid; b < K; b += 256)
        hist[blockIdx.x * MAXK + b] = lh[b];     // coalesced private row
}

// ---- pass B0: bucket totals (parallel, coalesced) + zero outacc -----------
__global__ __launch_bounds__(256) void totals_kernel(
        const int* __restrict__ hist, int* __restrict__ bts,
        float* __restrict__ outacc, int K, int G2) {
    int g0 = blockIdx.x * 256 + threadIdx.x;
    int stride = gridDim.x * 256;
    for (int i = g0; i < G2; i += stride) outacc[i] = 0.f;
    for (int b = g0; b < K; b += stride) {
        int s = 0;
        for (int blk = 0; blk < NBLK; ++blk) s += hist[blk * MAXK + b];
        bts[b] = s;
    }
}

// ---- pass B1: exclusive scan of bts[K] -> bb; bb[K] = E -------------------
__global__ __launch_bounds__(256) void scan_bb_kernel(
        const int* __restrict__ bts, int* __restrict__ bb, int K, int E) {
    __shared__ int part[256];
    int tid = threadIdx.x;
    int CH2 = (K + 255) / 256;
    int base = tid * CH2;
    int s = 0;
    for (int i = 0; i < CH2; ++i) {
        int idx = base + i;
        if (idx < K) s += bts[idx];
    }
    part[tid] = s;
    __syncthreads();
    if (tid < 64) {
        int carry = 0;
        for (int c = 0; c < 4; ++c) {
            int orig = part[c * 64 + tid];
            int v = orig;
            #pragma unroll
            for (int off = 1; off < 64; off <<= 1) {
                int t = __shfl_up(v, off);
                if (tid >= off) v += t;
            }
            int tot = __shfl(v, 63);
            part[c * 64 + tid] = v - orig + carry;   // exclusive
            carry += tot;
        }
    }
    __syncthreads();
    int run = part[tid];
    for (int i = 0; i < CH2; ++i) {
        int idx = base + i;
        if (idx < K) {
            bb[idx] = run;
            run += bts[idx];
        }
    }
    if (tid == 0) bb[K] = E;
}

// ---- pass B2: one WAVE per bucket scans across blocks -> cur[blk][bucket] -
__global__ __launch_bounds__(256) void scanB_kernel(
        const int* __restrict__ hist, const int* __restrict__ bb,
        int* __restrict__ cur, int K) {
    int wid = (blockIdx.x * 256 + threadIdx.x) >> 6;   // global wave id = bucket
    int lane = threadIdx.x & 63;
    if (wid >= K) return;
    int b = wid;
    int v0 = hist[(lane * 4 + 0) * MAXK + b];
    int v1 = hist[(lane * 4 + 1) * MAXK + b];
    int v2 = hist[(lane * 4 + 2) * MAXK + b];
    int v3 = hist[(lane * 4 + 3) * MAXK + b];
    int sum = v0 + v1 + v2 + v3;
    int pref = sum;
    #pragma unroll
    for (int off = 1; off < 64; off <<= 1) {
        int t = __shfl_up(pref, off);
        if (lane >= off) pref += t;
    }
    int run = bb[b] + pref - sum;   // exclusive
    cur[(lane * 4 + 0) * MAXK + b] = run; run += v0;
    cur[(lane * 4 + 1) * MAXK + b] = run; run += v1;
    cur[(lane * 4 + 2) * MAXK + b] = run; run += v2;
    cur[(lane * 4 + 3) * MAXK + b] = run;
}

// ---- pass C: append packed pairs; cursors in LDS (block-private cells) ----
__global__ __launch_bounds__(256) void fill_kernel(
        const int* __restrict__ src, const int* __restrict__ dst, int E, int CH,
        const int* __restrict__ cur, int* __restrict__ pairbuf, int K) {
    __shared__ int lcur[MAXK];
    int tid = threadIdx.x;
    for (int b = tid; b < K; b += 256)
        lcur[b] = cur[blockIdx.x * MAXK + b];
    __syncthreads();
    int e0 = blockIdx.x * CH;
    int e1 = min(E, e0 + CH);
    for (int e = e0 + tid; e < e1; e += 256) {
        int s = src[e], d = dst[e];
        int pos = atomicAdd(&lcur[((unsigned)d) >> 8], 1);
        pairbuf[pos] = s | ((d & 255) << 24);
    }
}

// ---- pass D: per-bucket padded CSR build + rowinfo/xd (coalesced) ---------
__global__ __launch_bounds__(256) void build_csr_kernel(
        const int* __restrict__ pairbuf, const int* __restrict__ bnd,
        const int* __restrict__ x, int2* __restrict__ rowinfo,
        float2* __restrict__ xd,
        int* __restrict__ csr_src, __half* __restrict__ g1h, int N) {
    __shared__ int cnt[256], basel[256], curl[256];
    int tid = threadIdx.x;
    int b = blockIdx.x;
    int node0 = b << 8;
    cnt[tid] = 0;
    __syncthreads();
    int bb0 = bnd[b], bb1 = bnd[b + 1];
    for (int i = bb0 + tid; i < bb1; i += 256)
        atomicAdd(&cnt[((unsigned)pairbuf[i]) >> 24], 1);
    __syncthreads();
    int c  = cnt[tid];
    int pc = (c + 3) & ~3;              // padded count
    {
        __syncthreads();
        basel[tid] = pc;
        __syncthreads();
        if (tid < 64) {
            int carry = 0;
            for (int cc = 0; cc < 4; ++cc) {
                int orig = basel[cc * 64 + tid];
                int v = orig;
                #pragma unroll
                for (int off = 1; off < 64; off <<= 1) {
                    int t = __shfl_up(v, off);
                    if (tid >= off) v += t;
                }
                int tot = __shfl(v, 63);
                cnt[cc * 64 + tid] = v - orig + carry;   // exclusive
                carry += tot;
            }
        }
        __syncthreads();
    }
    int cb0 = ((bb0 + 3) & ~3) + SLACK * b;   // aligned csr base for bucket
    int node = node0 + tid;
    int myBase = cb0 + cnt[tid];
    curl[tid] = myBase;
    if (node < N) {
        rowinfo[node] = make_int2(myBase, pc);
        xd[node] = make_float2(rsqrtf((float)c + 1.0f), __int_as_float(x[node]));
        for (int t = c; t < pc; ++t) csr_src[myBase + t] = N;   // sentinel pad
    } else if (node == N) {
        xd[N] = make_float2(0.0f, __int_as_float(0));           // zero weight
        float2* z = (float2*)(g1h + (size_t)N * DD);            // zero row N
        for (int t = 0; t < DD / 4; ++t) z[t] = make_float2(0.f, 0.f);
    }
    __syncthreads();
    for (int i = bb0 + tid; i < bb1; i += 256) {
        int pk = pairbuf[i];
        int pos = atomicAdd(&curl[((unsigned)pk) >> 24], 1);
        csr_src[pos] = pk & 0x00FFFFFF;
    }
}

// ---------------- layer 1: agg from fp16 table, MFMA MLP, g1h = f16(dv*h1) --
// 8 lanes/node, b128 chunks; unroll x2 (8 rows in flight); Hs stride 9.
__global__ __launch_bounds__(256, 6) void layer1_kernel(
        const int2* __restrict__ rowinfo,
        const int* __restrict__ csr_src, const float2* __restrict__ xd,
        const float4* __restrict__ th4, const __half* __restrict__ wt,
        const float* __restrict__ bias, __half* __restrict__ g1h, int N) {
    __shared__ float4 Hs4[32 * 9];   // padded stride 9
    __shared__ float dvs[32];
    int row0 = blockIdx.x * 32;
    int tid = threadIdx.x;
    int node_l = tid >> 3, j3 = tid & 7;
    int node = row0 + node_l;
    H8 acc0, acc1, acc2, acc3;
    acc0.f = make_float4(0.f, 0.f, 0.f, 0.f);
    acc1.f = acc0.f; acc2.f = acc0.f; acc3.f = acc0.f;
    __half2 dh = __float2half2_rn(0.f);
    if (node < N) {
        float2 sxd = xd[node];
        float di = sxd.x;
        if (j3 == 0) dvs[node_l] = di;
        dh = __float2half2_rn(di);
        H8 tv; tv.f = th4[(size_t)__float_as_int(sxd.y) * 8 + j3];
        acc0.h[0] = __hmul2(dh, tv.h[0]); acc0.h[1] = __hmul2(dh, tv.h[1]);
        acc0.h[2] = __hmul2(dh, tv.h[2]); acc0.h[3] = __hmul2(dh, tv.h[3]);
        int2 ri = rowinfo[node];
        const int4* cs = (const int4*)(csr_src + ri.x);
        int nq = ri.y >> 2;
        int q = 0;
        for (; q + 1 < nq; q += 2) {
            int4 sA = cs[q], sB = cs[q + 1];
            float2 pa = xd[sA.x], pb = xd[sA.y], pc_ = xd[sA.z], pd = xd[sA.w];
            float2 pe = xd[sB.x], pf = xd[sB.y], pg = xd[sB.z], ph = xd[sB.w];
            H8 u0, u1, u2, u3, u4, u5, u6, u7;
            u0.f = th4[(size_t)__float_as_int(pa.y)  * 8 + j3];
            u1.f = th4[(size_t)__float_as_int(pb.y)  * 8 + j3];
            u2.f = th4[(size_t)__float_as_int(pc_.y) * 8 + j3];
            u3.f = th4[(size_t)__float_as_int(pd.y)  * 8 + j3];
            u4.f = th4[(size_t)__float_as_int(pe.y)  * 8 + j3];
            u5.f = th4[(size_t)__float_as_int(pf.y)  * 8 + j3];
            u6.f = th4[(size_t)__float_as_int(pg.y)  * 8 + j3];
            u7.f = th4[(size_t)__float_as_int(ph.y)  * 8 + j3];
            __half2 w0 = __float2half2_rn(pa.x), w1 = __float2half2_rn(pb.x);
            __half2 w2 = __float2half2_rn(pc_.x), w3 = __float2half2_rn(pd.x);
            __half2 w4 = __float2half2_rn(pe.x), w5 = __float2half2_rn(pf.x);
            __half2 w6 = __float2half2_rn(pg.x), w7 = __float2half2_rn(ph.x);
            #pragma unroll
            for (int t = 0; t < 4; ++t) {
                acc0.h[t] = __hfma2(w0, u0.h[t], acc0.h[t]);
                acc1.h[t] = __hfma2(w1, u1.h[t], acc1.h[t]);
                acc2.h[t] = __hfma2(w2, u2.h[t], acc2.h[t]);
                acc3.h[t] = __hfma2(w3, u3.h[t], acc3.h[t]);
                acc0.h[t] = __hfma2(w4, u4.h[t], acc0.h[t]);
                acc1.h[t] = __hfma2(w5, u5.h[t], acc1.h[t]);
                acc2.h[t] = __hfma2(w6, u6.h[t], acc2.h[t]);
                acc3.h[t] = __hfma2(w7, u7.h[t], acc3.h[t]);
            }
        }
        if (q < nq) {
            int4 sA = cs[q];
            float2 pa = xd[sA.x], pb = xd[sA.y], pc_ = xd[sA.z], pd = xd[sA.w];
            H8 u0, u1, u2, u3;
            u0.f = th4[(size_t)__float_as_int(pa.y)  * 8 + j3];
            u1.f = th4[(size_t)__float_as_int(pb.y)  * 8 + j3];
            u2.f = th4[(size_t)__float_as_int(pc_.y) * 8 + j3];
            u3.f = th4[(size_t)__float_as_int(pd.y)  * 8 + j3];
            __half2 w0 = __float2half2_rn(pa.x), w1 = __float2half2_rn(pb.x);
            __half2 w2 = __float2half2_rn(pc_.x), w3 = __float2half2_rn(pd.x);
            #pragma unroll
            for (int t = 0; t < 4; ++t) {
                acc0.h[t] = __hfma2(w0, u0.h[t], acc0.h[t]);
                acc1.h[t] = __hfma2(w1, u1.h[t], acc1.h[t]);
                acc2.h[t] = __hfma2(w2, u2.h[t], acc2.h[t]);
                acc3.h[t] = __hfma2(w3, u3.h[t], acc3.h[t]);
            }
        }
        #pragma unroll
        for (int t = 0; t < 4; ++t)
            acc0.h[t] = __hmul2(dh, __hadd2(__hadd2(acc0.h[t], acc1.h[t]),
                                            __hadd2(acc2.h[t], acc3.h[t])));
    }
    Hs4[node_l * 9 + j3] = acc0.f;
    __syncthreads();

    // MFMA MLP: 2 tiles of 16 rows; each wave does cols wave*16..+15, K=64.
    int wave = tid >> 6, lane = tid & 63;
    int m = lane & 15, quad = lane >> 4;
    int ncol = wave * 16 + m;
    F4H8 b0, b1;
    const float4* WT4 = (const float4*)wt;
    b0.f = WT4[ncol * 8 + quad];
    b1.f = WT4[ncol * 8 + 4 + quad];
    float bb_ = bias[ncol];
    #pragma unroll
    for (int t = 0; t < 2; ++t) {
        F4H8 a0, a1;
        a0.f = Hs4[(t * 16 + m) * 9 + quad];
        a1.f = Hs4[(t * 16 + m) * 9 + 4 + quad];
        float4_t acc = {0.f, 0.f, 0.f, 0.f};
        acc = __builtin_amdgcn_mfma_f32_16x16x32_f16(a0.h, b0.h, acc, 0, 0, 0);
        acc = __builtin_amdgcn_mfma_f32_16x16x32_f16(a1.h, b1.h, acc, 0, 0, 0);
        #pragma unroll
        for (int reg = 0; reg < 4; ++reg) {
            int row = t * 16 + quad * 4 + reg;
            int grow = row0 + row;
            if (grow < N) {
                float h = fmaxf(acc[reg] + bb_, 0.0f);
                g1h[(size_t)grow * DD + ncol] = __float2half(dvs[row] * h);
            }
        }
    }
}

// -------- layer 2 + pool: gather g1h, MFMA MLP, Wlin dot + segmented pool ---
__global__ __launch_bounds__(256, 6) void layer2_pool_kernel(
        const int2* __restrict__ rowinfo,
        const int* __restrict__ csr_src, const float2* __restrict__ xd,
        const float4* __restrict__ g1h4, const __half* __restrict__ wt,
        const float* __restrict__ bias, const int* __restrict__ batch,
        const float* __restrict__ Wlin, float* __restrict__ outacc, int N) {
    __shared__ float4 Hs4[32 * 9];       // padded stride 9
    __shared__ float lp0[128], lp1[128]; // [wave][row]
    __shared__ float p0s[32], p1s[32];
    __shared__ int   bat[32];
    int row0 = blockIdx.x * 32;
    int tid = threadIdx.x;
    int node_l = tid >> 3, j3 = tid & 7;
    int node = row0 + node_l;
    H8 acc0, acc1, acc2, acc3;
    acc0.f = make_float4(0.f, 0.f, 0.f, 0.f);
    acc1.f = acc0.f; acc2.f = acc0.f; acc3.f = acc0.f;
    if (node < N) {
        float di = xd[node].x;
        acc0.f = g1h4[(size_t)node * 8 + j3];   // self term, weight 1
        int2 ri = rowinfo[node];
        const int4* cs = (const int4*)(csr_src + ri.x);
        int nq = ri.y >> 2;
        int q = 0;
        for (; q + 1 < nq; q += 2) {
            int4 sA = cs[q], sB = cs[q + 1];
            H8 u0, u1, u2, u3, u4, u5, u6, u7;
            u0.f = g1h4[(size_t)sA.x * 8 + j3];
            u1.f = g1h4[(size_t)sA.y * 8 + j3];
            u2.f = g1h4[(size_t)sA.z * 8 + j3];
            u3.f = g1h4[(size_t)sA.w * 8 + j3];
            u4.f = g1h4[(size_t)sB.x * 8 + j3];
            u5.f = g1h4[(size_t)sB.y * 8 + j3];
            u6.f = g1h4[(size_t)sB.z * 8 + j3];
            u7.f = g1h4[(size_t)sB.w * 8 + j3];
            #pragma unroll
            for (int t = 0; t < 4; ++t) {
                acc0.h[t] = __hadd2(acc0.h[t], u0.h[t]);
                acc1.h[t] = __hadd2(acc1.h[t], u1.h[t]);
                acc2.h[t] = __hadd2(acc2.h[t], u2.h[t]);
                acc3.h[t] = __hadd2(acc3.h[t], u3.h[t]);
                acc0.h[t] = __hadd2(acc0.h[t], u4.h[t]);
                acc1.h[t] = __hadd2(acc1.h[t], u5.h[t]);
                acc2.h[t] = __hadd2(acc2.h[t], u6.h[t]);
                acc3.h[t] = __hadd2(acc3.h[t], u7.h[t]);
            }
        }
        if (q < nq) {
            int4 sA = cs[q];
            H8 u0, u1, u2, u3;
            u0.f = g1h4[(size_t)sA.x * 8 + j3];
            u1.f = g1h4[(size_t)sA.y * 8 + j3];
            u2.f = g1h4[(size_t)sA.z * 8 + j3];
            u3.f = g1h4[(size_t)sA.w * 8 + j3];
            #pragma unroll
            for (int t = 0; t < 4; ++t) {
                acc0.h[t] = __hadd2(acc0.h[t], u0.h[t]);
                acc1.h[t] = __hadd2(acc1.h[t], u1.h[t]);
                acc2.h[t] = __hadd2(acc2.h[t], u2.h[t]);
                acc3.h[t] = __hadd2(acc3.h[t], u3.h[t]);
            }
        }
        __half2 dih = __float2half2_rn(di);
        #pragma unroll
        for (int t = 0; t < 4; ++t)
            acc0.h[t] = __hmul2(dih, __hadd2(__hadd2(acc0.h[t], acc1.h[t]),
                                             __hadd2(acc2.h[t], acc3.h[t])));
    }
    Hs4[node_l * 9 + j3] = acc0.f;
    __syncthreads();

    int wave = tid >> 6, lane = tid & 63;
    int m = lane & 15, quad = lane >> 4;
    int ncol = wave * 16 + m;
    F4H8 b0, b1;
    const float4* WT4 = (const float4*)wt;
    b0.f = WT4[ncol * 8 + quad];
    b1.f = WT4[ncol * 8 + 4 + quad];
    float bb_  = bias[ncol];
    float wl0 = Wlin[ncol * 2 + 0];
    float wl1 = Wlin[ncol * 2 + 1];
    #pragma unroll
    for (int t = 0; t < 2; ++t) {
        F4H8 a0, a1;
        a0.f = Hs4[(t * 16 + m) * 9 + quad];
        a1.f = Hs4[(t * 16 + m) * 9 + 4 + quad];
        float4_t acc = {0.f, 0.f, 0.f, 0.f};
        acc = __builtin_amdgcn_mfma_f32_16x16x32_f16(a0.h, b0.h, acc, 0, 0, 0);
        acc = __builtin_amdgcn_mfma_f32_16x16x32_f16(a1.h, b1.h, acc, 0, 0, 0);
        #pragma unroll
        for (int reg = 0; reg < 4; ++reg) {
            int row = t * 16 + quad * 4 + reg;
            int grow = row0 + row;
            float h = (grow < N) ? fmaxf(acc[reg] + bb_, 0.0f) : 0.0f;
            float p0 = h * wl0;
            float p1 = h * wl1;
            #pragma unroll
            for (int off = 8; off >= 1; off >>= 1) {   // sum over 16 cols (m)
                p0 += __shfl_xor(p0, off);
                p1 += __shfl_xor(p1, off);
            }
            if (m == 0) {
                lp0[wave * 32 + row] = p0;
                lp1[wave * 32 + row] = p1;
            }
        }
    }
    __syncthreads();
    if (tid < 32) {
        int grow = row0 + tid;
        p0s[tid] = lp0[tid] + lp0[32 + tid] + lp0[64 + tid] + lp0[96 + tid];
        p1s[tid] = lp1[tid] + lp1[32 + tid] + lp1[64 + tid] + lp1[96 + tid];
        bat[tid] = (grow < N) ? batch[grow] : -1;
    }
    __syncthreads();
    if (tid < 32) {
        int bg = bat[tid];
        bool head = (bg >= 0) && (tid == 0 || bat[tid - 1] != bg);
        if (head) {
            float s0 = 0.f, s1 = 0.f;
            for (int k = tid; k < 32 && bat[k] == bg; ++k) {
                s0 += p0s[k];
                s1 += p1s[k];
            }
            atomAddF(&outacc[bg * 2 + 0], s0);
            atomAddF(&outacc[bg * 2 + 1], s1);
        }
    }
}

// counts via binary search on sorted batch; then divide + blin
__global__ void final_kernel(const float* __restrict__ outacc,
                             const int* __restrict__ batch,
                             const float* __restrict__ blin,
                             float* __restrict__ out, int G, int N) {
    int t = blockIdx.x * blockDim.x + threadIdx.x;
    if (t >= G * 2) return;
    int g = t >> 1, c = t & 1;
    int lo = 0, hi = N;
    while (lo < hi) { int m = (lo + hi) >> 1; if (batch[m] < g) lo = m + 1; else hi = m; }
    int lo2 = lo, hi2 = N;
    while (lo2 < hi2) { int m = (lo2 + hi2) >> 1; if (batch[m] < g + 1) lo2 = m + 1; else hi2 = m; }
    float cnt = (float)(lo2 - lo);
    out[t] = outacc[t] / fmaxf(cnt, 1.0f) + blin[c];
}

extern "C" void kernel_launch(void* const* d_in, const int* in_sizes, int n_in,
                              void* d_out, int out_size, void* d_ws, size_t ws_size,
                              hipStream_t stream) {
    const int*   x      = (const int*)d_in[0];
    const int*   ei     = (const int*)d_in[1];   // [2,E] row-major
    const int*   batch  = (const int*)d_in[3];
    const float* table  = (const float*)d_in[4];
    const float* W1     = (const float*)d_in[5];
    const float* b1     = (const float*)d_in[6];
    const float* W2     = (const float*)d_in[7];
    const float* b2     = (const float*)d_in[8];
    const float* Wlin   = (const float*)d_in[9];
    const float* blin   = (const float*)d_in[10];
    float* out = (float*)d_out;

    const int N = in_sizes[0];
    const int E = in_sizes[2];          // edge_type count == E
    const int G = out_size / 2;
    const int TBL = in_sizes[4];        // VOCAB*DD floats

    const int* src = ei;
    const int* dst = ei + E;

    const int K = (N + BKT - 1) / BKT;  // buckets
    const int M = NBLK * MAXK;          // (block, bucket) cells
    const int CH = (E + NBLK - 1) / NBLK;
    const int CSRSZ = E + SLACK * K + 64;

    // workspace layout (keep 16-B alignment for b128 reads)
    __half* g1h     = (__half*)d_ws;                      // (N+1)*64 halves
    __half* th      = g1h + (size_t)(N + 1) * DD;         // TBL halves
    __half* w1t     = th + TBL;                           // 4096 halves
    __half* w2t     = w1t + DD * DD;                      // 4096 halves
    int*    pairbuf = (int*)(w2t + DD * DD);              // E ints
    int*    csr_src = pairbuf + E;                        // CSRSZ ints
    int2*   rowinfo = (int2*)(csr_src + CSRSZ);           // N int2
    float2* xd      = (float2*)(rowinfo + N);             // N+1 float2
    float*  outacc  = (float*)(xd + N + 1);               // 2G (zeroed in totals)
    int*    bb      = (int*)(outacc + 2 * G);             // K+1
    int*    bts     = bb + K + 1;                         // K
    int*    hist    = bts + K;                            // M
    int*    cur     = hist + M;                           // M

    const int BT = 256;

    // partition: per-chunk histogram -> totals(+outacc zero) -> bucket scan
    //            -> per-bucket block scan (wave-parallel) -> append -> sort
    bin_count_kernel<<<NBLK, BT, 0, stream>>>(dst, E, CH, hist, K,
                                              (const float2*)table,
                                              (__half2*)th, TBL / 2,
                                              W1, W2, w1t, w2t);
    totals_kernel<<<16, BT, 0, stream>>>(hist, bts, outacc, K, 2 * G);
    scan_bb_kernel<<<1, BT, 0, stream>>>(bts, bb, K, E);
    scanB_kernel<<<(K * 64 + BT - 1) / BT, BT, 0, stream>>>(hist, bb, cur, K);
    fill_kernel<<<NBLK, BT, 0, stream>>>(src, dst, E, CH, cur, pairbuf, K);
    build_csr_kernel<<<K, BT, 0, stream>>>(pairbuf, bb, x, rowinfo, xd,
                                           csr_src, g1h, N);

    // layer 1 (embed+agg+MFMA-MLP+relu fused; writes g1h = fp16(dinv*h1))
    int gRow = (N + 31) / 32;
    layer1_kernel<<<gRow, BT, 0, stream>>>(rowinfo, csr_src, xd,
                                           (const float4*)th, w1t, b1, g1h, N);
    // layer 2 (agg+MFMA-MLP+relu+pool fused)
    layer2_pool_kernel<<<gRow, BT, 0, stream>>>(rowinfo, csr_src, xd,
                                                (const float4*)g1h, w2t, b2,
                                                batch, Wlin, outacc, N);
    // final
    final_kernel<<<(G * 2 + BT - 1) / BT, BT, 0, stream>>>(outacc, batch, blin,
                                                           out, G, N);
}